// Round 4
// baseline (185.282 us; speedup 1.0000x reference)
//
#include <hip/hip_runtime.h>
#include <math.h>

#define Bv 4
#define Nv 3136
#define Cv 64
#define Hh 56
#define Ww 56
#define HIDv 256
#define TOPKv 8
#define TSP 520   // msfn ts row pitch (bf16): dword pitch % 32 == 4 -> conflict-free b128
#define LCP 584   // im2col row pitch (576+8): same property
#define XNP 72    // ln/proj LDS bf16 row pitch (64+8): dword pitch 36 % 32 == 4
#define KSPL 16   // key splits in k_attn_topk
#define KPS 196   // keys per split (3136/16)

constexpr float SCALE = 0.125f;   // d^-0.5, d=64
constexpr float EPS = 1e-5f;
constexpr float SBIAS = 128.0f;   // score bias: all packed scores positive

typedef short bf16x8 __attribute__((ext_vector_type(8)));
typedef float f32x4 __attribute__((ext_vector_type(4)));

#define CSWAP(a, b) { unsigned int _hi = max(a, b); unsigned int _lo = min(a, b); a = _hi; b = _lo; }
// descending bitonic clean of 8 (input: bitonic), 3 stages
#define BITONIC8(T) \
  CSWAP(T[0], T[4]); CSWAP(T[1], T[5]); CSWAP(T[2], T[6]); CSWAP(T[3], T[7]); \
  CSWAP(T[0], T[2]); CSWAP(T[1], T[3]); CSWAP(T[4], T[6]); CSWAP(T[5], T[7]); \
  CSWAP(T[0], T[1]); CSWAP(T[2], T[3]); CSWAP(T[4], T[5]); CSWAP(T[6], T[7]);

__device__ __forceinline__ unsigned short f2bf(float f) {
  unsigned int u = __float_as_uint(f);
  u = (u + 0x7FFFu + ((u >> 16) & 1u)) >> 16;
  return (unsigned short)u;
}
__device__ __forceinline__ float bf2f(unsigned short u) {
  return __uint_as_float(((unsigned int)u) << 16);
}
__device__ __forceinline__ unsigned int pack2(float a, float b) {
  return (unsigned int)f2bf(a) | ((unsigned int)f2bf(b) << 16);
}

// biased-positive pack: score s is already s+SBIAS (>0), bits monotone as uint
__device__ __forceinline__ unsigned int packB(float sb, int j) {
  return (__float_as_uint(sb) & 0xFFFFF000u) | (unsigned int)j;
}

// ---------------- K0: weight prep (+ sumv zero) -----------------------------
__global__ void k_transpose(const float* __restrict__ w1, const float* __restrict__ lw,
                            const float* __restrict__ w3, const float* __restrict__ w5,
                            const float* __restrict__ wq, const float* __restrict__ wkv,
                            const float* __restrict__ bq, const float* __restrict__ bkv,
                            const float* __restrict__ wproj,
                            unsigned short* __restrict__ w1bf, unsigned short* __restrict__ lwb,
                            float* __restrict__ w3t, float* __restrict__ w5t,
                            unsigned short* __restrict__ wqkvt, float* __restrict__ qkvb,
                            unsigned short* __restrict__ wprojt, float* __restrict__ sumv) {
  int p = blockIdx.x * 256 + threadIdx.x;
  if (p < 256) sumv[p] = 0.0f;
  if (p < 64 * 512) w1bf[p] = f2bf(w1[p]);
  if (p < 64 * 576) {
    int co = p / 576, k = p % 576;
    int tap = k >> 6, ci = k & 63;
    lwb[p] = f2bf(lw[co * 576 + ci * 9 + tap]);
  }
  if (p < 36 * 64) {
    int cin = p & 63, tm = p >> 6;
    int tap = tm >> 2, m = tm & 3;
    w3t[p] = w3[(cin * 4 + m) * 9 + tap];
  }
  if (p < 100 * 64) {
    int cin = p & 63, tm = p >> 6;
    int tap = tm >> 2, m = tm & 3;
    w5t[p] = w5[(cin * 4 + m) * 25 + tap];
  }
  if (p < 192 * 64) {
    int o = p >> 6, i = p & 63;
    float v = (o < 64) ? wq[i * 64 + o] : wkv[i * 128 + (o - 64)];
    wqkvt[p] = f2bf(v);
  }
  if (p < 192) qkvb[p] = (p < 64) ? bq[p] : bkv[p - 64];
  if (p < 64 * 64) {
    int o = p >> 6, i = p & 63;
    wprojt[p] = f2bf(wproj[i * 64 + o]);
  }
}

// ---------------- K1: LN1 + QKV via MFMA (16 tokens/block) + V-sum ----------
__global__ __launch_bounds__(256) void k_ln_qkv(
    const float* __restrict__ x, const float* __restrict__ g1, const float* __restrict__ b1,
    const unsigned short* __restrict__ wqkvt, const float* __restrict__ qkvb,
    unsigned short* __restrict__ q16, unsigned short* __restrict__ k16,
    float* __restrict__ vo, float* __restrict__ sumv) {
  __shared__ __align__(16) unsigned short xnS[16 * XNP];
  int bid = blockIdx.x;
  int b = bid / 196, tile = bid % 196;
  size_t tok0 = (size_t)b * Nv + tile * 16;
  int t = threadIdx.x;
  int w = t >> 6, l = t & 63;
  int tokL = t >> 4;        // 0..15
  int ch0 = (t & 15) * 4;
  size_t tok = tok0 + tokL;
  float v[4];
  *(float4*)v = *(const float4*)&x[tok * 64 + ch0];
  float s = v[0] + v[1] + v[2] + v[3];
  float s2 = v[0] * v[0] + v[1] * v[1] + v[2] * v[2] + v[3] * v[3];
#pragma unroll
  for (int off = 1; off <= 8; off <<= 1) {
    s += __shfl_xor(s, off, 64);
    s2 += __shfl_xor(s2, off, 64);
  }
  float m = s * (1.f / 64.f);
  float rs = rsqrtf(s2 * (1.f / 64.f) - m * m + EPS);
  {
    unsigned int pk[2];
    float a0_ = (v[0] - m) * rs * g1[ch0] + b1[ch0];
    float a1_ = (v[1] - m) * rs * g1[ch0 + 1] + b1[ch0 + 1];
    float a2_ = (v[2] - m) * rs * g1[ch0 + 2] + b1[ch0 + 2];
    float a3_ = (v[3] - m) * rs * g1[ch0 + 3] + b1[ch0 + 3];
    pk[0] = pack2(a0_, a1_);
    pk[1] = pack2(a2_, a3_);
    *(uint2*)&xnS[tokL * XNP + ch0] = *(uint2*)pk;
  }
  __syncthreads();
  int n = l & 15, q = l >> 4;
  const bf16x8 a0 = *(const bf16x8*)&xnS[n * XNP + q * 8];
  const bf16x8 a1 = *(const bf16x8*)&xnS[n * XNP + 32 + q * 8];
  // Q tile j=w
  {
    const unsigned short* wr = &wqkvt[(size_t)(w * 16 + n) * 64];
    bf16x8 b0 = *(const bf16x8*)&wr[q * 8];
    bf16x8 b1_ = *(const bf16x8*)&wr[32 + q * 8];
    f32x4 acc = {0.f, 0.f, 0.f, 0.f};
    acc = __builtin_amdgcn_mfma_f32_16x16x32_bf16(a0, b0, acc, 0, 0, 0);
    acc = __builtin_amdgcn_mfma_f32_16x16x32_bf16(a1, b1_, acc, 0, 0, 0);
    float bias = qkvb[w * 16 + n];
#pragma unroll
    for (int r = 0; r < 4; ++r)
      q16[(tok0 + q * 4 + r) * 64 + w * 16 + n] = f2bf(acc[r] + bias);
  }
  // K tile j=w
  {
    const unsigned short* wr = &wqkvt[(size_t)((w + 4) * 16 + n) * 64];
    bf16x8 b0 = *(const bf16x8*)&wr[q * 8];
    bf16x8 b1_ = *(const bf16x8*)&wr[32 + q * 8];
    f32x4 acc = {0.f, 0.f, 0.f, 0.f};
    acc = __builtin_amdgcn_mfma_f32_16x16x32_bf16(a0, b0, acc, 0, 0, 0);
    acc = __builtin_amdgcn_mfma_f32_16x16x32_bf16(a1, b1_, acc, 0, 0, 0);
    float bias = qkvb[64 + w * 16 + n];
#pragma unroll
    for (int r = 0; r < 4; ++r)
      k16[(tok0 + q * 4 + r) * 64 + w * 16 + n] = f2bf(acc[r] + bias);
  }
  // V tile j=w + fused per-batch column sum
  {
    const unsigned short* wr = &wqkvt[(size_t)((w + 8) * 16 + n) * 64];
    bf16x8 b0 = *(const bf16x8*)&wr[q * 8];
    bf16x8 b1_ = *(const bf16x8*)&wr[32 + q * 8];
    f32x4 acc = {0.f, 0.f, 0.f, 0.f};
    acc = __builtin_amdgcn_mfma_f32_16x16x32_bf16(a0, b0, acc, 0, 0, 0);
    acc = __builtin_amdgcn_mfma_f32_16x16x32_bf16(a1, b1_, acc, 0, 0, 0);
    float bias = qkvb[128 + w * 16 + n];
    float vp = acc[0] + acc[1] + acc[2] + acc[3] + 4.0f * bias;
#pragma unroll
    for (int r = 0; r < 4; ++r)
      vo[(tok0 + q * 4 + r) * 64 + w * 16 + n] = acc[r] + bias;
    vp += __shfl_xor(vp, 16, 64);
    vp += __shfl_xor(vp, 32, 64);
    if (q == 0) atomicAdd(&sumv[b * 64 + w * 16 + n], vp);
  }
}

// ---------------- K2a: 4-tile-per-wave pair-batched top-8 (16 key splits) ---
// block=128 = 2 independent waves; wave job = (tilegroup of 4 tiles, split).
// K fragments loaded once per chunk-pair and reused for 4 query tiles.
// DEPTH-2 PREFETCH: two chunk-pairs (8 b128 loads) in flight, so the
// consume-wait for pair i lands ~2 compute-pairs (~1700cy) after issue —
// covers cross-XCD L3 latency (k16 is written by all XCDs).
#define PAIRMERGE(T, accA, accB, jb) { \
    unsigned int _p0 = packB(accA[0], (jb) + 0); \
    unsigned int _p1 = packB(accA[1], (jb) + 1); \
    unsigned int _p2 = packB(accA[2], (jb) + 2); \
    unsigned int _p3 = packB(accA[3], (jb) + 3); \
    unsigned int _q0 = packB(accB[0], (jb) + 16); \
    unsigned int _q1 = packB(accB[1], (jb) + 17); \
    unsigned int _q2 = packB(accB[2], (jb) + 18); \
    unsigned int _q3 = packB(accB[3], (jb) + 19); \
    CSWAP(_p0, _p1); CSWAP(_p2, _p3); CSWAP(_p0, _p2); CSWAP(_p1, _p3); CSWAP(_p1, _p2); \
    CSWAP(_q0, _q1); CSWAP(_q2, _q3); CSWAP(_q0, _q2); CSWAP(_q1, _q3); CSWAP(_q1, _q2); \
    unsigned int _u8[8] = {_p0, _p1, _p2, _p3, _q3, _q2, _q1, _q0}; \
    BITONIC8(_u8); \
    T[0] = max(T[0], _u8[7]); \
    T[1] = max(T[1], _u8[6]); \
    T[2] = max(T[2], _u8[5]); \
    T[3] = max(T[3], _u8[4]); \
    T[4] = max(T[4], _u8[3]); \
    T[5] = max(T[5], _u8[2]); \
    T[6] = max(T[6], _u8[1]); \
    T[7] = max(T[7], _u8[0]); \
    BITONIC8(T); }

#define CONSUME_PAIR(A0, A1, B0, B1) { \
    _Pragma("unroll") \
    for (int tt = 0; tt < 4; ++tt) { \
      f32x4 accA = {SBIAS, SBIAS, SBIAS, SBIAS}; \
      accA = __builtin_amdgcn_mfma_f32_16x16x32_bf16(A0, qf0a[tt], accA, 0, 0, 0); \
      accA = __builtin_amdgcn_mfma_f32_16x16x32_bf16(A1, qf1a[tt], accA, 0, 0, 0); \
      f32x4 accB = {SBIAS, SBIAS, SBIAS, SBIAS}; \
      accB = __builtin_amdgcn_mfma_f32_16x16x32_bf16(B0, qf0a[tt], accB, 0, 0, 0); \
      accB = __builtin_amdgcn_mfma_f32_16x16x32_bf16(B1, qf1a[tt], accB, 0, 0, 0); \
      PAIRMERGE(t8[tt], accA, accB, jbA); \
    } \
    jbA += 32; }

__global__ __launch_bounds__(128, 3) void k_attn_topk(
    const unsigned short* __restrict__ q16, const unsigned short* __restrict__ k16,
    unsigned int* __restrict__ top8out) {
  int bid = blockIdx.x;
  int w = threadIdx.x >> 6;
  int lane = threadIdx.x & 63;
  int split = ((bid & 7) << 1) | w;   // 0..15
  int lin = bid >> 3;                 // 0..195
  int b = lin / 49, tg = lin % 49;    // tilegroup of 4 tiles
  int qbase = b * Nv + tg * 64;
  size_t bN = (size_t)b * Nv;
  int qcol = lane & 15, quad = lane >> 4;
  int quad4 = quad * 4;

  bf16x8 qf0a[4], qf1a[4];
#pragma unroll
  for (int tt = 0; tt < 4; ++tt) {
    qf0a[tt] = *(const bf16x8*)&q16[((size_t)(qbase + tt * 16 + qcol)) * 64 + quad * 8];
    qf1a[tt] = *(const bf16x8*)&q16[((size_t)(qbase + tt * 16 + qcol)) * 64 + 32 + quad * 8];
  }

  unsigned int t8[4][8];
#pragma unroll
  for (int tt = 0; tt < 4; ++tt)
#pragma unroll
    for (int u = 0; u < 8; ++u) t8[tt][u] = 0u;

  int kbase = split * KPS;   // KPS=196
  int m = lane & 15;
  const char* kbp = (const char*)(k16 + bN * 64);
  unsigned int offA = (unsigned int)((kbase + m) * 128 + quad * 16);
  int jbA = kbase + quad4;

  // depth-2 prologue: pairs 0 and 1 both in flight
  bf16x8 p0a0 = *(const bf16x8*)(kbp + offA);
  bf16x8 p0a1 = *(const bf16x8*)(kbp + offA + 64);
  bf16x8 p0b0 = *(const bf16x8*)(kbp + offA + 2048);
  bf16x8 p0b1 = *(const bf16x8*)(kbp + offA + 2112);
  offA += 4096;
  bf16x8 p1a0 = *(const bf16x8*)(kbp + offA);
  bf16x8 p1a1 = *(const bf16x8*)(kbp + offA + 64);
  bf16x8 p1b0 = *(const bf16x8*)(kbp + offA + 2048);
  bf16x8 p1b1 = *(const bf16x8*)(kbp + offA + 2112);
  offA += 4096;

#pragma unroll 1
  for (int it = 0; it < 2; ++it) {  // consumes pairs 0..3, issues pairs 2..5
    {
      bf16x8 ca0 = p0a0, ca1 = p0a1, cb0 = p0b0, cb1 = p0b1;
      p0a0 = *(const bf16x8*)(kbp + offA);
      p0a1 = *(const bf16x8*)(kbp + offA + 64);
      p0b0 = *(const bf16x8*)(kbp + offA + 2048);
      p0b1 = *(const bf16x8*)(kbp + offA + 2112);
      offA += 4096;
      CONSUME_PAIR(ca0, ca1, cb0, cb1);
    }
    {
      bf16x8 ca0 = p1a0, ca1 = p1a1, cb0 = p1b0, cb1 = p1b1;
      p1a0 = *(const bf16x8*)(kbp + offA);
      p1a1 = *(const bf16x8*)(kbp + offA + 64);
      p1b0 = *(const bf16x8*)(kbp + offA + 2048);
      p1b1 = *(const bf16x8*)(kbp + offA + 2112);
      offA += 4096;
      CONSUME_PAIR(ca0, ca1, cb0, cb1);
    }
  }

  {  // peeled pair 4 (keys 128..159); prefetch ragged chunk 12 (chain A only)
    bf16x8 ca0 = p0a0, ca1 = p0a1, cb0 = p0b0, cb1 = p0b1;
    p0a0 = *(const bf16x8*)(kbp + offA);
    p0a1 = *(const bf16x8*)(kbp + offA + 64);
    CONSUME_PAIR(ca0, ca1, cb0, cb1);
  }

  {  // peeled pair 5 (keys 160..191)
    CONSUME_PAIR(p1a0, p1a1, p1b0, p1b1);
  }

  {  // ragged chunk 12: keys 192..195 of split valid (per-element klim mask)
    int klim = kbase + KPS;
#pragma unroll
    for (int tt = 0; tt < 4; ++tt) {
      f32x4 accA = {SBIAS, SBIAS, SBIAS, SBIAS};
      accA = __builtin_amdgcn_mfma_f32_16x16x32_bf16(p0a0, qf0a[tt], accA, 0, 0, 0);
      accA = __builtin_amdgcn_mfma_f32_16x16x32_bf16(p0a1, qf1a[tt], accA, 0, 0, 0);
      unsigned int p0 = (jbA + 0 < klim) ? packB(accA[0], jbA + 0) : 0u;
      unsigned int p1 = (jbA + 1 < klim) ? packB(accA[1], jbA + 1) : 0u;
      unsigned int p2 = (jbA + 2 < klim) ? packB(accA[2], jbA + 2) : 0u;
      unsigned int p3 = (jbA + 3 < klim) ? packB(accA[3], jbA + 3) : 0u;
      CSWAP(p0, p1); CSWAP(p2, p3); CSWAP(p0, p2); CSWAP(p1, p3); CSWAP(p1, p2);
      t8[tt][4] = max(t8[tt][4], p3);
      t8[tt][5] = max(t8[tt][5], p2);
      t8[tt][6] = max(t8[tt][6], p1);
      t8[tt][7] = max(t8[tt][7], p0);
      BITONIC8(t8[tt]);
    }
  }

  // merge across quads (same query col): butterfly xor 16, 32 — per tile
#pragma unroll
  for (int tt = 0; tt < 4; ++tt) {
#pragma unroll
    for (int step = 16; step <= 32; step <<= 1) {
      unsigned int o[8];
#pragma unroll
      for (int i = 0; i < 8; ++i) o[i] = (unsigned int)__shfl_xor((int)t8[tt][i], step, 64);
      unsigned int nw[8];
#pragma unroll
      for (int i = 0; i < 8; ++i) nw[i] = max(t8[tt][i], o[7 - i]);
#pragma unroll
      for (int i = 0; i < 8; ++i) t8[tt][i] = nw[i];
      BITONIC8(t8[tt]);
    }
    if (quad == 0) {
      size_t obase = ((size_t)(bN + tg * 64 + tt * 16 + qcol)) * 128 + split * 8;
      *(uint4*)&top8out[obase] = make_uint4(t8[tt][0], t8[tt][1], t8[tt][2], t8[tt][3]);
      *(uint4*)&top8out[obase + 4] = make_uint4(t8[tt][4], t8[tt][5], t8[tt][6], t8[tt][7]);
    }
  }
}

// ---- K2b: 16-list merge + PV + local-conv(fused) + proj + LN1 + res + LN2 --
// Phase A runs on wave 0 (4 lanes/token x 4 lists + 2-step butterfly),
// OVERLAPPED with im2col staging on waves 1-3. Phase B's 32 scattered vg
// gathers are issued before the conv MFMA loop so their latency hides.
__global__ __launch_bounds__(256) void k_attn_proj(
    const unsigned int* __restrict__ top8, const float* __restrict__ vg,
    const float* __restrict__ sumv, const float* __restrict__ x,
    const unsigned short* __restrict__ lwb, const float* __restrict__ lb,
    const unsigned short* __restrict__ wprojt, const float* __restrict__ bproj,
    const float* __restrict__ g1, const float* __restrict__ b1,
    const float* __restrict__ g2, const float* __restrict__ b2,
    float* __restrict__ x2, unsigned short* __restrict__ xn2b) {
  __shared__ float kwS[16][8];
  __shared__ int kidxS[16][8];
  __shared__ float invZS[16];
  __shared__ __align__(16) unsigned short imS[16 * LCP];
  __shared__ __align__(16) unsigned short gS[16 * XNP];
  __shared__ float yS[16 * 66];
  int bid = blockIdx.x;
  int b = bid / 196, rem = bid % 196;
  int th = rem / 7, tw = rem % 7;
  int h0 = th * 2, w0 = tw * 8;
  size_t bN = (size_t)b * Nv;
  int t = threadIdx.x;

  if (t < 64) {
    // Phase A (wave 0): parallel 16-list merge. lane group la=t&3 merges
    // lists 4*la..4*la+3 for token tk=t>>2, then butterfly xor 1,2.
    int tk = t >> 2, la = t & 3;
    int gtok = (h0 + (tk >> 3)) * Ww + w0 + (tk & 7);
    size_t base = (bN + gtok) * 128 + la * 32;
    unsigned int A[8];
#pragma unroll
    for (int i = 0; i < 8; ++i) A[i] = top8[base + i];
#pragma unroll
    for (int h = 1; h < 4; ++h) {
      unsigned int Bb[8];
#pragma unroll
      for (int i = 0; i < 8; ++i) Bb[i] = top8[base + h * 8 + i];
#pragma unroll
      for (int i = 0; i < 8; ++i) A[i] = max(A[i], Bb[7 - i]);
      BITONIC8(A);
    }
#pragma unroll
    for (int step = 1; step <= 2; step <<= 1) {
      unsigned int o[8];
#pragma unroll
      for (int i = 0; i < 8; ++i) o[i] = (unsigned int)__shfl_xor((int)A[i], step, 64);
#pragma unroll
      for (int i = 0; i < 8; ++i) A[i] = max(A[i], o[7 - i]);
      BITONIC8(A);
    }
    if (la == 0) {
      float Z = (float)(Nv - TOPKv);
#pragma unroll
      for (int u = 0; u < 8; ++u) {
        float sb = __uint_as_float(A[u] & 0xFFFFF000u);
        float s = (sb - SBIAS) * SCALE;
        float e = __expf(s);
        kwS[tk][u] = e - 1.0f;
        kidxS[tk][u] = (int)(A[u] & 0xFFFu);
        Z += e;
      }
      invZS[tk] = 1.0f / Z;
    }
  } else {
    // im2col staging from fp32 x (bf16 inline), waves 1-3: 1152/192 = 6 rounds
    for (int p = t - 64; p < 1152; p += 192) {
      int sub = p & 7, s = p >> 3;
      int tok = s / 9, tap = s % 9;
      int tr = tok >> 3, tc = tok & 7;
      int dh = tap / 3, dw = tap % 3;
      int gh = h0 + tr - 1 + dh, gw = w0 + tc - 1 + dw;
      uint4 uu = {0u, 0u, 0u, 0u};
      if (gh >= 0 && gh < Hh && gw >= 0 && gw < Ww) {
        const float* xp = &x[(bN + gh * Ww + gw) * 64 + sub * 8];
        float4 va = *(const float4*)xp;
        float4 vb = *(const float4*)(xp + 4);
        uu.x = pack2(va.x, va.y);
        uu.y = pack2(va.z, va.w);
        uu.z = pack2(vb.x, vb.y);
        uu.w = pack2(vb.z, vb.w);
      }
      *(uint4*)&imS[tok * LCP + tap * 64 + sub * 8] = uu;
    }
  }
  __syncthreads();

  int w = t >> 6, l = t & 63;
  int n = l & 15, q = l >> 4;

  // Phase B part 1: issue the 32 scattered vg gathers (latency hides under conv)
  int c = t & 63, rg = t >> 6;
  float vgv[4][8];
#pragma unroll
  for (int rr = 0; rr < 4; ++rr) {
    int tokL = rg * 4 + rr;
#pragma unroll
    for (int u = 0; u < 8; ++u)
      vgv[rr][u] = vg[(bN + kidxS[tokL][u]) * 64 + c];
  }

  // local conv MFMA (18 per wave), result in registers
  f32x4 lacc = {0.f, 0.f, 0.f, 0.f};
  {
    const unsigned short* lwrow = &lwb[(size_t)(w * 16 + n) * 576];
#pragma unroll 6
    for (int kk = 0; kk < 18; ++kk) {
      bf16x8 af = *(const bf16x8*)&imS[n * LCP + kk * 32 + q * 8];
      bf16x8 bfr = *(const bf16x8*)&lwrow[kk * 32 + q * 8];
      lacc = __builtin_amdgcn_mfma_f32_16x16x32_bf16(af, bfr, lacc, 0, 0, 0);
    }
  }
  float lbias = lb[w * 16 + n];

  // Phase B part 2: g = (sumv + sum_top8 (e^s-1) v)/Z -> gS (bf16)
  {
    float sv = sumv[b * 64 + c];
#pragma unroll
    for (int rr = 0; rr < 4; ++rr) {
      int tokL = rg * 4 + rr;
      float acc = sv;
#pragma unroll
      for (int u = 0; u < 8; ++u)
        acc += kwS[tokL][u] * vgv[rr][u];
      gS[tokL * XNP + c] = f2bf(acc * invZS[tokL]);
    }
  }
  __syncthreads();

  // Phase C: proj GEMM + add local conv, y -> yS
  {
    const bf16x8 a0 = *(const bf16x8*)&gS[n * XNP + q * 8];
    const bf16x8 a1 = *(const bf16x8*)&gS[n * XNP + 32 + q * 8];
    const unsigned short* wr = &wprojt[(size_t)(w * 16 + n) * 64];
    bf16x8 b0 = *(const bf16x8*)&wr[q * 8];
    bf16x8 b1_ = *(const bf16x8*)&wr[32 + q * 8];
    f32x4 acc = {0.f, 0.f, 0.f, 0.f};
    acc = __builtin_amdgcn_mfma_f32_16x16x32_bf16(a0, b0, acc, 0, 0, 0);
    acc = __builtin_amdgcn_mfma_f32_16x16x32_bf16(a1, b1_, acc, 0, 0, 0);
    float bias = bproj[w * 16 + n];
#pragma unroll
    for (int r = 0; r < 4; ++r)
      yS[(q * 4 + r) * 66 + w * 16 + n] = acc[r] + bias + lacc[r] + lbias;
  }
  __syncthreads();

  // Phase D: LN1 -> residual -> LN2 (16-lane group per token, 4 ch each)
  int tokL = t >> 4;
  int ch0 = (t & 15) * 4;
  size_t tok = bN + (size_t)(h0 + (tokL >> 3)) * Ww + w0 + (tokL & 7);
  float y[4];
#pragma unroll
  for (int i = 0; i < 4; ++i) y[i] = yS[tokL * 66 + ch0 + i];
  float s = y[0] + y[1] + y[2] + y[3];
  float s2 = y[0] * y[0] + y[1] * y[1] + y[2] * y[2] + y[3] * y[3];
#pragma unroll
  for (int off = 1; off <= 8; off <<= 1) {
    s += __shfl_xor(s, off, 64);
    s2 += __shfl_xor(s2, off, 64);
  }
  float m1 = s * (1.f / 64.f);
  float rs1 = rsqrtf(s2 * (1.f / 64.f) - m1 * m1 + EPS);
  float xv[4];
  *(float4*)xv = *(const float4*)&x[tok * 64 + ch0];
  float x2v[4];
  float t_s = 0.f, t_s2 = 0.f;
#pragma unroll
  for (int i = 0; i < 4; ++i) {
    float t1 = (y[i] - m1) * rs1 * g1[ch0 + i] + b1[ch0 + i];
    x2v[i] = xv[i] + t1;
    t_s += x2v[i];
    t_s2 += x2v[i] * x2v[i];
  }
#pragma unroll
  for (int off = 1; off <= 8; off <<= 1) {
    t_s += __shfl_xor(t_s, off, 64);
    t_s2 += __shfl_xor(t_s2, off, 64);
  }
  float m2 = t_s * (1.f / 64.f);
  float rs2 = rsqrtf(t_s2 * (1.f / 64.f) - m2 * m2 + EPS);
  *(float4*)&x2[tok * 64 + ch0] = *(float4*)x2v;
  unsigned int pk[2];
  {
    float a0_ = (x2v[0] - m2) * rs2 * g2[ch0] + b2[ch0];
    float a1_ = (x2v[1] - m2) * rs2 * g2[ch0 + 1] + b2[ch0 + 1];
    float a2_ = (x2v[2] - m2) * rs2 * g2[ch0 + 2] + b2[ch0 + 2];
    float a3_ = (x2v[3] - m2) * rs2 * g2[ch0 + 3] + b2[ch0 + 3];
    pk[0] = pack2(a0_, a1_);
    pk[1] = pack2(a2_, a3_);
  }
  *(uint2*)&xn2b[tok * 64 + ch0] = *(uint2*)pk;
}

// ---------------- K5: MSFN — depthwise in regs, 1x1 via MFMA ----------------
// Window loads now DIRECT from global xn2b (lane=cin -> coalesced 128B rows,
// wave-uniform bounds) — removes the xtS LDS staging + 40 ds_read_u16/thread
// + one __syncthreads.
__global__ __launch_bounds__(256) void k_msfn(
    const unsigned short* __restrict__ xn2b, const float* __restrict__ x2,
    const float* __restrict__ w3t, const float* __restrict__ b3,
    const float* __restrict__ w5t, const float* __restrict__ b5,
    const unsigned short* __restrict__ w1bf, const float* __restrict__ b1,
    float* __restrict__ out) {
  __shared__ __align__(16) unsigned short tsS[16 * TSP];

  int bid = blockIdx.x;
  int b = bid / 196;
  int rem = bid % 196;
  int th = rem / 7, tw = rem % 7;
  int h0 = th * 2, w0 = tw * 8;
  size_t bN = (size_t)b * Nv;
  int t = threadIdx.x;

  int cin = t & 63, tg = t >> 6;
  int tr = tg >> 1, tc0 = (tg & 1) * 4;
  float win[5][8];
  {
    const unsigned short* xb = xn2b + bN * 64 + cin;
    int gw0 = w0 - 2 + tc0;
#pragma unroll
    for (int r = 0; r < 5; ++r) {
      int gh = h0 - 2 + tr + r;
      if (gh >= 0 && gh < Hh) {
        const unsigned short* rowp = xb + ((size_t)gh * Ww + gw0) * 64;
#pragma unroll
        for (int c = 0; c < 8; ++c) {
          int gw = gw0 + c;
          win[r][c] = (gw >= 0 && gw < Ww) ? bf2f(rowp[c * 64]) : 0.0f;
        }
      } else {
#pragma unroll
        for (int c = 0; c < 8; ++c) win[r][c] = 0.0f;
      }
    }
  }

  unsigned int* tsU = (unsigned int*)tsS;
#pragma unroll 1
  for (int m2 = 0; m2 < 4; m2 += 2) {
    float a3[2][9], a5[2][25], bb3[2], bb5[2];
#pragma unroll
    for (int mm = 0; mm < 2; ++mm) {
      int m = m2 + mm;
#pragma unroll
      for (int tap = 0; tap < 9; ++tap) a3[mm][tap] = w3t[(tap * 4 + m) * 64 + cin];
#pragma unroll
      for (int tap = 0; tap < 25; ++tap) a5[mm][tap] = w5t[(tap * 4 + m) * 64 + cin];
      bb3[mm] = b3[cin * 4 + m];
      bb5[mm] = b5[cin * 4 + m];
    }
#pragma unroll
    for (int tk = 0; tk < 4; ++tk) {
      int tok = tg * 4 + tk;
      unsigned int p3 = 0, p5 = 0;
#pragma unroll
      for (int mm = 0; mm < 2; ++mm) {
        float acc3 = bb3[mm];
#pragma unroll
        for (int kh = 0; kh < 3; ++kh)
#pragma unroll
          for (int kw2 = 0; kw2 < 3; ++kw2)
            acc3 += win[1 + kh][tk + 1 + kw2] * a3[mm][kh * 3 + kw2];
        float acc5 = bb5[mm];
#pragma unroll
        for (int kh = 0; kh < 5; ++kh)
#pragma unroll
          for (int kw2 = 0; kw2 < 5; ++kw2)
            acc5 += win[kh][tk + kw2] * a5[mm][kh * 5 + kw2];
        p3 |= (unsigned int)f2bf(acc3) << (16 * mm);
        p5 |= (unsigned int)f2bf(acc5) << (16 * mm);
      }
      tsU[(tok * TSP + cin * 4 + m2) >> 1] = p3;
      tsU[(tok * TSP + 256 + cin * 4 + m2) >> 1] = p5;
    }
  }
  __syncthreads();

  int wv = tg, lane = t & 63;
  int n16 = lane & 15, quad = lane >> 4;
  const unsigned short* wrow = &w1bf[(size_t)(wv * 16 + n16) * 512];
  f32x4 acc = {0.f, 0.f, 0.f, 0.f};
#pragma unroll 4
  for (int kk = 0; kk < 16; ++kk) {
    bf16x8 af = *(const bf16x8*)&tsS[n16 * TSP + kk * 32 + quad * 8];
    bf16x8 bfr = *(const bf16x8*)&wrow[kk * 32 + quad * 8];
    acc = __builtin_amdgcn_mfma_f32_16x16x32_bf16(af, bfr, acc, 0, 0, 0);
  }
  float bias = b1[wv * 16 + n16];
#pragma unroll
  for (int r = 0; r < 4; ++r) {
    int tok = quad * 4 + r;
    int trr = tok >> 3, tcc = tok & 7;
    size_t idx = (bN + (size_t)(h0 + trr) * Ww + w0 + tcc) * 64 + wv * 16 + n16;
    out[idx] = x2[idx] + acc[r] + bias;
  }
}

extern "C" void kernel_launch(void* const* d_in, const int* in_sizes, int n_in,
                              void* d_out, int out_size, void* d_ws, size_t ws_size,
                              hipStream_t stream) {
  const float* x = (const float*)d_in[0];
  const float* n1g = (const float*)d_in[1];
  const float* n1b = (const float*)d_in[2];
  const float* wq = (const float*)d_in[3];
  const float* bq = (const float*)d_in[4];
  const float* wkv = (const float*)d_in[5];
  const float* bkv = (const float*)d_in[6];
  const float* wproj = (const float*)d_in[7];
  const float* bproj = (const float*)d_in[8];
  const float* lw = (const float*)d_in[9];
  const float* lb = (const float*)d_in[10];
  const float* n2g = (const float*)d_in[11];
  const float* n2b = (const float*)d_in[12];
  const float* w3 = (const float*)d_in[13];
  const float* b3 = (const float*)d_in[14];
  const float* w5 = (const float*)d_in[15];
  const float* b5 = (const float*)d_in[16];
  const float* w1 = (const float*)d_in[17];
  const float* b1 = (const float*)d_in[18];
  float* out = (float*)d_out;

  float* ws = (float*)d_ws;
  const size_t TOK = (size_t)Bv * Nv * Cv;  // 802816
  float* vb = ws;
  float* sumv = vb + TOK;            // 256
  float* x2 = sumv + 256;
  float* w3t = x2 + TOK;             // 2304
  float* w5t = w3t + 2304;           // 6400
  float* qkvb = w5t + 6400;          // 192
  unsigned short* q16 = (unsigned short*)(qkvb + 192);
  unsigned short* k16 = q16 + TOK;
  unsigned short* xn2b = k16 + TOK;
  unsigned short* w1bf = xn2b + TOK;       // 64*512
  unsigned short* lwb = w1bf + 64 * 512;   // 64*576
  unsigned short* wqkvt = lwb + 64 * 576;  // 192*64
  unsigned short* wprojt = wqkvt + 192 * 64;  // 64*64
  unsigned int* top8ws = (unsigned int*)(wprojt + 64 * 64 + 64);  // 12544*128 uints

  k_transpose<<<144, 256, 0, stream>>>(w1, lw, w3, w5, wq, wkv, bq, bkv, wproj,
                                       w1bf, lwb, w3t, w5t, wqkvt, qkvb, wprojt, sumv);
  k_ln_qkv<<<Bv * 196, 256, 0, stream>>>(x, n1g, n1b, wqkvt, qkvb, q16, k16, vb, sumv);
  k_attn_topk<<<Bv * 49 * 8, 128, 0, stream>>>(q16, k16, top8ws);
  k_attn_proj<<<Bv * 196, 256, 0, stream>>>(top8ws, vb, sumv, x, lwb, lb, wprojt, bproj,
                                            n1g, n1b, n2g, n2b, x2, xn2b);
  k_msfn<<<Bv * 196, 256, 0, stream>>>(xn2b, x2, w3t, b3, w5t, b5, w1bf, b1, out);
}

// Round 5
// 181.477 us; speedup vs baseline: 1.0210x; 1.0210x over previous
//
#include <hip/hip_runtime.h>
#include <math.h>

#define Bv 4
#define Nv 3136
#define Cv 64
#define Hh 56
#define Ww 56
#define HIDv 256
#define TOPKv 8
#define TSP 520   // msfn ts row pitch (bf16): dword pitch % 32 == 4 -> conflict-free b128
#define LCP 584   // im2col row pitch (576+8): same property
#define XNP 72    // ln/proj LDS bf16 row pitch (64+8): dword pitch 36 % 32 == 4
#define KSPL 16   // key splits in k_attn_topk
#define KPS 196   // keys per split (3136/16)

constexpr float SCALE = 0.125f;   // d^-0.5, d=64
constexpr float EPS = 1e-5f;
constexpr float SBIAS = 128.0f;   // score bias: all packed scores positive

typedef short bf16x8 __attribute__((ext_vector_type(8)));
typedef float f32x4 __attribute__((ext_vector_type(4)));

#define CSWAP(a, b) { unsigned int _hi = max(a, b); unsigned int _lo = min(a, b); a = _hi; b = _lo; }
// descending bitonic clean of 8 (input: bitonic), 3 stages
#define BITONIC8(T) \
  CSWAP(T[0], T[4]); CSWAP(T[1], T[5]); CSWAP(T[2], T[6]); CSWAP(T[3], T[7]); \
  CSWAP(T[0], T[2]); CSWAP(T[1], T[3]); CSWAP(T[4], T[6]); CSWAP(T[5], T[7]); \
  CSWAP(T[0], T[1]); CSWAP(T[2], T[3]); CSWAP(T[4], T[5]); CSWAP(T[6], T[7]);

__device__ __forceinline__ unsigned short f2bf(float f) {
  unsigned int u = __float_as_uint(f);
  u = (u + 0x7FFFu + ((u >> 16) & 1u)) >> 16;
  return (unsigned short)u;
}
__device__ __forceinline__ float bf2f(unsigned short u) {
  return __uint_as_float(((unsigned int)u) << 16);
}
__device__ __forceinline__ unsigned int pack2(float a, float b) {
  return (unsigned int)f2bf(a) | ((unsigned int)f2bf(b) << 16);
}

// biased-positive pack: score s is already s+SBIAS (>0), bits monotone as uint
__device__ __forceinline__ unsigned int packB(float sb, int j) {
  return (__float_as_uint(sb) & 0xFFFFF000u) | (unsigned int)j;
}

// ---------------- K0: weight prep (+ sumv zero) -----------------------------
__global__ void k_transpose(const float* __restrict__ w1, const float* __restrict__ lw,
                            const float* __restrict__ w3, const float* __restrict__ w5,
                            const float* __restrict__ wq, const float* __restrict__ wkv,
                            const float* __restrict__ bq, const float* __restrict__ bkv,
                            const float* __restrict__ wproj,
                            unsigned short* __restrict__ w1bf, unsigned short* __restrict__ lwb,
                            float* __restrict__ w3t, float* __restrict__ w5t,
                            unsigned short* __restrict__ wqkvt, float* __restrict__ qkvb,
                            unsigned short* __restrict__ wprojt, float* __restrict__ sumv) {
  int p = blockIdx.x * 256 + threadIdx.x;
  if (p < 256) sumv[p] = 0.0f;
  if (p < 64 * 512) w1bf[p] = f2bf(w1[p]);
  if (p < 64 * 576) {
    int co = p / 576, k = p % 576;
    int tap = k >> 6, ci = k & 63;
    lwb[p] = f2bf(lw[co * 576 + ci * 9 + tap]);
  }
  if (p < 36 * 64) {
    int cin = p & 63, tm = p >> 6;
    int tap = tm >> 2, m = tm & 3;
    w3t[p] = w3[(cin * 4 + m) * 9 + tap];
  }
  if (p < 100 * 64) {
    int cin = p & 63, tm = p >> 6;
    int tap = tm >> 2, m = tm & 3;
    w5t[p] = w5[(cin * 4 + m) * 25 + tap];
  }
  if (p < 192 * 64) {
    int o = p >> 6, i = p & 63;
    float v = (o < 64) ? wq[i * 64 + o] : wkv[i * 128 + (o - 64)];
    wqkvt[p] = f2bf(v);
  }
  if (p < 192) qkvb[p] = (p < 64) ? bq[p] : bkv[p - 64];
  if (p < 64 * 64) {
    int o = p >> 6, i = p & 63;
    wprojt[p] = f2bf(wproj[i * 64 + o]);
  }
}

// ---------------- K1: LN1 + QKV via MFMA (16 tokens/block) + V-sum ----------
__global__ __launch_bounds__(256) void k_ln_qkv(
    const float* __restrict__ x, const float* __restrict__ g1, const float* __restrict__ b1,
    const unsigned short* __restrict__ wqkvt, const float* __restrict__ qkvb,
    unsigned short* __restrict__ q16, unsigned short* __restrict__ k16,
    float* __restrict__ vo, float* __restrict__ sumv) {
  __shared__ __align__(16) unsigned short xnS[16 * XNP];
  int bid = blockIdx.x;
  int b = bid / 196, tile = bid % 196;
  size_t tok0 = (size_t)b * Nv + tile * 16;
  int t = threadIdx.x;
  int w = t >> 6, l = t & 63;
  int tokL = t >> 4;        // 0..15
  int ch0 = (t & 15) * 4;
  size_t tok = tok0 + tokL;
  float v[4];
  *(float4*)v = *(const float4*)&x[tok * 64 + ch0];
  float s = v[0] + v[1] + v[2] + v[3];
  float s2 = v[0] * v[0] + v[1] * v[1] + v[2] * v[2] + v[3] * v[3];
#pragma unroll
  for (int off = 1; off <= 8; off <<= 1) {
    s += __shfl_xor(s, off, 64);
    s2 += __shfl_xor(s2, off, 64);
  }
  float m = s * (1.f / 64.f);
  float rs = rsqrtf(s2 * (1.f / 64.f) - m * m + EPS);
  {
    unsigned int pk[2];
    float a0_ = (v[0] - m) * rs * g1[ch0] + b1[ch0];
    float a1_ = (v[1] - m) * rs * g1[ch0 + 1] + b1[ch0 + 1];
    float a2_ = (v[2] - m) * rs * g1[ch0 + 2] + b1[ch0 + 2];
    float a3_ = (v[3] - m) * rs * g1[ch0 + 3] + b1[ch0 + 3];
    pk[0] = pack2(a0_, a1_);
    pk[1] = pack2(a2_, a3_);
    *(uint2*)&xnS[tokL * XNP + ch0] = *(uint2*)pk;
  }
  __syncthreads();
  int n = l & 15, q = l >> 4;
  const bf16x8 a0 = *(const bf16x8*)&xnS[n * XNP + q * 8];
  const bf16x8 a1 = *(const bf16x8*)&xnS[n * XNP + 32 + q * 8];
  // Q tile j=w
  {
    const unsigned short* wr = &wqkvt[(size_t)(w * 16 + n) * 64];
    bf16x8 b0 = *(const bf16x8*)&wr[q * 8];
    bf16x8 b1_ = *(const bf16x8*)&wr[32 + q * 8];
    f32x4 acc = {0.f, 0.f, 0.f, 0.f};
    acc = __builtin_amdgcn_mfma_f32_16x16x32_bf16(a0, b0, acc, 0, 0, 0);
    acc = __builtin_amdgcn_mfma_f32_16x16x32_bf16(a1, b1_, acc, 0, 0, 0);
    float bias = qkvb[w * 16 + n];
#pragma unroll
    for (int r = 0; r < 4; ++r)
      q16[(tok0 + q * 4 + r) * 64 + w * 16 + n] = f2bf(acc[r] + bias);
  }
  // K tile j=w
  {
    const unsigned short* wr = &wqkvt[(size_t)((w + 4) * 16 + n) * 64];
    bf16x8 b0 = *(const bf16x8*)&wr[q * 8];
    bf16x8 b1_ = *(const bf16x8*)&wr[32 + q * 8];
    f32x4 acc = {0.f, 0.f, 0.f, 0.f};
    acc = __builtin_amdgcn_mfma_f32_16x16x32_bf16(a0, b0, acc, 0, 0, 0);
    acc = __builtin_amdgcn_mfma_f32_16x16x32_bf16(a1, b1_, acc, 0, 0, 0);
    float bias = qkvb[64 + w * 16 + n];
#pragma unroll
    for (int r = 0; r < 4; ++r)
      k16[(tok0 + q * 4 + r) * 64 + w * 16 + n] = f2bf(acc[r] + bias);
  }
  // V tile j=w + fused per-batch column sum
  {
    const unsigned short* wr = &wqkvt[(size_t)((w + 8) * 16 + n) * 64];
    bf16x8 b0 = *(const bf16x8*)&wr[q * 8];
    bf16x8 b1_ = *(const bf16x8*)&wr[32 + q * 8];
    f32x4 acc = {0.f, 0.f, 0.f, 0.f};
    acc = __builtin_amdgcn_mfma_f32_16x16x32_bf16(a0, b0, acc, 0, 0, 0);
    acc = __builtin_amdgcn_mfma_f32_16x16x32_bf16(a1, b1_, acc, 0, 0, 0);
    float bias = qkvb[128 + w * 16 + n];
    float vp = acc[0] + acc[1] + acc[2] + acc[3] + 4.0f * bias;
#pragma unroll
    for (int r = 0; r < 4; ++r)
      vo[(tok0 + q * 4 + r) * 64 + w * 16 + n] = acc[r] + bias;
    vp += __shfl_xor(vp, 16, 64);
    vp += __shfl_xor(vp, 32, 64);
    if (q == 0) atomicAdd(&sumv[b * 64 + w * 16 + n], vp);
  }
}

// ---------------- K2a: 4-tile-per-wave pair-batched top-8 (16 key splits) ---
// block=128 = 2 independent waves; wave job = (tilegroup of 4 tiles, split).
// K fragments loaded once per chunk-pair and reused for 4 query tiles
// (4x less K cache traffic, 4x VALU work per load). Depth-1 prefetch ONLY:
// depth-2 (+16-32 VGPR) breached the launch_bounds(128,3) ~170-VGPR cap and
// spilled in the hot loop (R4: +14us). Do not deepen without dropping tiles.
#define PAIRMERGE(T, accA, accB, jb) { \
    unsigned int _p0 = packB(accA[0], (jb) + 0); \
    unsigned int _p1 = packB(accA[1], (jb) + 1); \
    unsigned int _p2 = packB(accA[2], (jb) + 2); \
    unsigned int _p3 = packB(accA[3], (jb) + 3); \
    unsigned int _q0 = packB(accB[0], (jb) + 16); \
    unsigned int _q1 = packB(accB[1], (jb) + 17); \
    unsigned int _q2 = packB(accB[2], (jb) + 18); \
    unsigned int _q3 = packB(accB[3], (jb) + 19); \
    CSWAP(_p0, _p1); CSWAP(_p2, _p3); CSWAP(_p0, _p2); CSWAP(_p1, _p3); CSWAP(_p1, _p2); \
    CSWAP(_q0, _q1); CSWAP(_q2, _q3); CSWAP(_q0, _q2); CSWAP(_q1, _q3); CSWAP(_q1, _q2); \
    unsigned int _u8[8] = {_p0, _p1, _p2, _p3, _q3, _q2, _q1, _q0}; \
    BITONIC8(_u8); \
    T[0] = max(T[0], _u8[7]); \
    T[1] = max(T[1], _u8[6]); \
    T[2] = max(T[2], _u8[5]); \
    T[3] = max(T[3], _u8[4]); \
    T[4] = max(T[4], _u8[3]); \
    T[5] = max(T[5], _u8[2]); \
    T[6] = max(T[6], _u8[1]); \
    T[7] = max(T[7], _u8[0]); \
    BITONIC8(T); }

__global__ __launch_bounds__(128, 3) void k_attn_topk(
    const unsigned short* __restrict__ q16, const unsigned short* __restrict__ k16,
    unsigned int* __restrict__ top8out) {
  int bid = blockIdx.x;
  int w = threadIdx.x >> 6;
  int lane = threadIdx.x & 63;
  int split = ((bid & 7) << 1) | w;   // 0..15
  int lin = bid >> 3;                 // 0..195
  int b = lin / 49, tg = lin % 49;    // tilegroup of 4 tiles
  int qbase = b * Nv + tg * 64;
  size_t bN = (size_t)b * Nv;
  int qcol = lane & 15, quad = lane >> 4;
  int quad4 = quad * 4;

  bf16x8 qf0a[4], qf1a[4];
#pragma unroll
  for (int tt = 0; tt < 4; ++tt) {
    qf0a[tt] = *(const bf16x8*)&q16[((size_t)(qbase + tt * 16 + qcol)) * 64 + quad * 8];
    qf1a[tt] = *(const bf16x8*)&q16[((size_t)(qbase + tt * 16 + qcol)) * 64 + 32 + quad * 8];
  }

  unsigned int t8[4][8];
#pragma unroll
  for (int tt = 0; tt < 4; ++tt)
#pragma unroll
    for (int u = 0; u < 8; ++u) t8[tt][u] = 0u;

  int kbase = split * KPS;   // KPS=196
  int m = lane & 15;
  const char* kbp = (const char*)(k16 + bN * 64);
  unsigned int offA = (unsigned int)((kbase + m) * 128 + quad * 16);
  int jbA = kbase + quad4;

  // prefetch chunk-pair 0 (chunks 0,1)
  bf16x8 ka0 = *(const bf16x8*)(kbp + offA);
  bf16x8 ka1 = *(const bf16x8*)(kbp + offA + 64);
  bf16x8 kb0 = *(const bf16x8*)(kbp + offA + 2048);
  bf16x8 kb1 = *(const bf16x8*)(kbp + offA + 2112);
  offA += 4096;

#pragma unroll 1
  for (int it = 0; it < 5; ++it) {  // pairs 0..4 consumed, prefetch pairs 1..5
    bf16x8 ca0 = ka0, ca1 = ka1, cb0 = kb0, cb1 = kb1;
    ka0 = *(const bf16x8*)(kbp + offA);
    ka1 = *(const bf16x8*)(kbp + offA + 64);
    kb0 = *(const bf16x8*)(kbp + offA + 2048);
    kb1 = *(const bf16x8*)(kbp + offA + 2112);
    offA += 4096;

#pragma unroll
    for (int tt = 0; tt < 4; ++tt) {
      f32x4 accA = {SBIAS, SBIAS, SBIAS, SBIAS};
      accA = __builtin_amdgcn_mfma_f32_16x16x32_bf16(ca0, qf0a[tt], accA, 0, 0, 0);
      accA = __builtin_amdgcn_mfma_f32_16x16x32_bf16(ca1, qf1a[tt], accA, 0, 0, 0);
      f32x4 accB = {SBIAS, SBIAS, SBIAS, SBIAS};
      accB = __builtin_amdgcn_mfma_f32_16x16x32_bf16(cb0, qf0a[tt], accB, 0, 0, 0);
      accB = __builtin_amdgcn_mfma_f32_16x16x32_bf16(cb1, qf1a[tt], accB, 0, 0, 0);
      PAIRMERGE(t8[tt], accA, accB, jbA);
    }
    jbA += 32;
  }

  {  // peeled pair 5 (keys 160..191); prefetch ragged chunk 12 (chain A only)
    bf16x8 ca0 = ka0, ca1 = ka1, cb0 = kb0, cb1 = kb1;
    ka0 = *(const bf16x8*)(kbp + offA);
    ka1 = *(const bf16x8*)(kbp + offA + 64);

#pragma unroll
    for (int tt = 0; tt < 4; ++tt) {
      f32x4 accA = {SBIAS, SBIAS, SBIAS, SBIAS};
      accA = __builtin_amdgcn_mfma_f32_16x16x32_bf16(ca0, qf0a[tt], accA, 0, 0, 0);
      accA = __builtin_amdgcn_mfma_f32_16x16x32_bf16(ca1, qf1a[tt], accA, 0, 0, 0);
      f32x4 accB = {SBIAS, SBIAS, SBIAS, SBIAS};
      accB = __builtin_amdgcn_mfma_f32_16x16x32_bf16(cb0, qf0a[tt], accB, 0, 0, 0);
      accB = __builtin_amdgcn_mfma_f32_16x16x32_bf16(cb1, qf1a[tt], accB, 0, 0, 0);
      PAIRMERGE(t8[tt], accA, accB, jbA);
    }
    jbA += 32;
  }

  {  // ragged chunk 12: keys 192..195 of split valid (per-element klim mask)
    int klim = kbase + KPS;
#pragma unroll
    for (int tt = 0; tt < 4; ++tt) {
      f32x4 accA = {SBIAS, SBIAS, SBIAS, SBIAS};
      accA = __builtin_amdgcn_mfma_f32_16x16x32_bf16(ka0, qf0a[tt], accA, 0, 0, 0);
      accA = __builtin_amdgcn_mfma_f32_16x16x32_bf16(ka1, qf1a[tt], accA, 0, 0, 0);
      unsigned int p0 = (jbA + 0 < klim) ? packB(accA[0], jbA + 0) : 0u;
      unsigned int p1 = (jbA + 1 < klim) ? packB(accA[1], jbA + 1) : 0u;
      unsigned int p2 = (jbA + 2 < klim) ? packB(accA[2], jbA + 2) : 0u;
      unsigned int p3 = (jbA + 3 < klim) ? packB(accA[3], jbA + 3) : 0u;
      CSWAP(p0, p1); CSWAP(p2, p3); CSWAP(p0, p2); CSWAP(p1, p3); CSWAP(p1, p2);
      t8[tt][4] = max(t8[tt][4], p3);
      t8[tt][5] = max(t8[tt][5], p2);
      t8[tt][6] = max(t8[tt][6], p1);
      t8[tt][7] = max(t8[tt][7], p0);
      BITONIC8(t8[tt]);
    }
  }

  // merge across quads (same query col): butterfly xor 16, 32 — per tile
#pragma unroll
  for (int tt = 0; tt < 4; ++tt) {
#pragma unroll
    for (int step = 16; step <= 32; step <<= 1) {
      unsigned int o[8];
#pragma unroll
      for (int i = 0; i < 8; ++i) o[i] = (unsigned int)__shfl_xor((int)t8[tt][i], step, 64);
      unsigned int nw[8];
#pragma unroll
      for (int i = 0; i < 8; ++i) nw[i] = max(t8[tt][i], o[7 - i]);
#pragma unroll
      for (int i = 0; i < 8; ++i) t8[tt][i] = nw[i];
      BITONIC8(t8[tt]);
    }
    if (quad == 0) {
      size_t obase = ((size_t)(bN + tg * 64 + tt * 16 + qcol)) * 128 + split * 8;
      *(uint4*)&top8out[obase] = make_uint4(t8[tt][0], t8[tt][1], t8[tt][2], t8[tt][3]);
      *(uint4*)&top8out[obase + 4] = make_uint4(t8[tt][4], t8[tt][5], t8[tt][6], t8[tt][7]);
    }
  }
}

// ---- K2b: 16-list merge + PV + local-conv(fused) + proj + LN1 + res + LN2 --
// Phase A runs on wave 0 (4 lanes/token x 4 lists + 2-step butterfly),
// OVERLAPPED with im2col staging on waves 1-3. Phase B's 32 scattered vg
// gathers are issued before the conv MFMA loop so their latency hides.
__global__ __launch_bounds__(256) void k_attn_proj(
    const unsigned int* __restrict__ top8, const float* __restrict__ vg,
    const float* __restrict__ sumv, const float* __restrict__ x,
    const unsigned short* __restrict__ lwb, const float* __restrict__ lb,
    const unsigned short* __restrict__ wprojt, const float* __restrict__ bproj,
    const float* __restrict__ g1, const float* __restrict__ b1,
    const float* __restrict__ g2, const float* __restrict__ b2,
    float* __restrict__ x2, unsigned short* __restrict__ xn2b) {
  __shared__ float kwS[16][8];
  __shared__ int kidxS[16][8];
  __shared__ float invZS[16];
  __shared__ __align__(16) unsigned short imS[16 * LCP];
  __shared__ __align__(16) unsigned short gS[16 * XNP];
  __shared__ float yS[16 * 66];
  int bid = blockIdx.x;
  int b = bid / 196, rem = bid % 196;
  int th = rem / 7, tw = rem % 7;
  int h0 = th * 2, w0 = tw * 8;
  size_t bN = (size_t)b * Nv;
  int t = threadIdx.x;

  if (t < 64) {
    // Phase A (wave 0): parallel 16-list merge. lane group la=t&3 merges
    // lists 4*la..4*la+3 for token tk=t>>2, then butterfly xor 1,2.
    int tk = t >> 2, la = t & 3;
    int gtok = (h0 + (tk >> 3)) * Ww + w0 + (tk & 7);
    size_t base = (bN + gtok) * 128 + la * 32;
    unsigned int A[8];
#pragma unroll
    for (int i = 0; i < 8; ++i) A[i] = top8[base + i];
#pragma unroll
    for (int h = 1; h < 4; ++h) {
      unsigned int Bb[8];
#pragma unroll
      for (int i = 0; i < 8; ++i) Bb[i] = top8[base + h * 8 + i];
#pragma unroll
      for (int i = 0; i < 8; ++i) A[i] = max(A[i], Bb[7 - i]);
      BITONIC8(A);
    }
#pragma unroll
    for (int step = 1; step <= 2; step <<= 1) {
      unsigned int o[8];
#pragma unroll
      for (int i = 0; i < 8; ++i) o[i] = (unsigned int)__shfl_xor((int)A[i], step, 64);
#pragma unroll
      for (int i = 0; i < 8; ++i) A[i] = max(A[i], o[7 - i]);
      BITONIC8(A);
    }
    if (la == 0) {
      float Z = (float)(Nv - TOPKv);
#pragma unroll
      for (int u = 0; u < 8; ++u) {
        float sb = __uint_as_float(A[u] & 0xFFFFF000u);
        float s = (sb - SBIAS) * SCALE;
        float e = __expf(s);
        kwS[tk][u] = e - 1.0f;
        kidxS[tk][u] = (int)(A[u] & 0xFFFu);
        Z += e;
      }
      invZS[tk] = 1.0f / Z;
    }
  } else {
    // im2col staging from fp32 x (bf16 inline), waves 1-3: 1152/192 = 6 rounds
    for (int p = t - 64; p < 1152; p += 192) {
      int sub = p & 7, s = p >> 3;
      int tok = s / 9, tap = s % 9;
      int tr = tok >> 3, tc = tok & 7;
      int dh = tap / 3, dw = tap % 3;
      int gh = h0 + tr - 1 + dh, gw = w0 + tc - 1 + dw;
      uint4 uu = {0u, 0u, 0u, 0u};
      if (gh >= 0 && gh < Hh && gw >= 0 && gw < Ww) {
        const float* xp = &x[(bN + gh * Ww + gw) * 64 + sub * 8];
        float4 va = *(const float4*)xp;
        float4 vb = *(const float4*)(xp + 4);
        uu.x = pack2(va.x, va.y);
        uu.y = pack2(va.z, va.w);
        uu.z = pack2(vb.x, vb.y);
        uu.w = pack2(vb.z, vb.w);
      }
      *(uint4*)&imS[tok * LCP + tap * 64 + sub * 8] = uu;
    }
  }
  __syncthreads();

  int w = t >> 6, l = t & 63;
  int n = l & 15, q = l >> 4;

  // Phase B part 1: issue the 32 scattered vg gathers (latency hides under conv)
  int c = t & 63, rg = t >> 6;
  float vgv[4][8];
#pragma unroll
  for (int rr = 0; rr < 4; ++rr) {
    int tokL = rg * 4 + rr;
#pragma unroll
    for (int u = 0; u < 8; ++u)
      vgv[rr][u] = vg[(bN + kidxS[tokL][u]) * 64 + c];
  }

  // local conv MFMA (18 per wave), result in registers
  f32x4 lacc = {0.f, 0.f, 0.f, 0.f};
  {
    const unsigned short* lwrow = &lwb[(size_t)(w * 16 + n) * 576];
#pragma unroll 6
    for (int kk = 0; kk < 18; ++kk) {
      bf16x8 af = *(const bf16x8*)&imS[n * LCP + kk * 32 + q * 8];
      bf16x8 bfr = *(const bf16x8*)&lwrow[kk * 32 + q * 8];
      lacc = __builtin_amdgcn_mfma_f32_16x16x32_bf16(af, bfr, lacc, 0, 0, 0);
    }
  }
  float lbias = lb[w * 16 + n];

  // Phase B part 2: g = (sumv + sum_top8 (e^s-1) v)/Z -> gS (bf16)
  {
    float sv = sumv[b * 64 + c];
#pragma unroll
    for (int rr = 0; rr < 4; ++rr) {
      int tokL = rg * 4 + rr;
      float acc = sv;
#pragma unroll
      for (int u = 0; u < 8; ++u)
        acc += kwS[tokL][u] * vgv[rr][u];
      gS[tokL * XNP + c] = f2bf(acc * invZS[tokL]);
    }
  }
  __syncthreads();

  // Phase C: proj GEMM + add local conv, y -> yS
  {
    const bf16x8 a0 = *(const bf16x8*)&gS[n * XNP + q * 8];
    const bf16x8 a1 = *(const bf16x8*)&gS[n * XNP + 32 + q * 8];
    const unsigned short* wr = &wprojt[(size_t)(w * 16 + n) * 64];
    bf16x8 b0 = *(const bf16x8*)&wr[q * 8];
    bf16x8 b1_ = *(const bf16x8*)&wr[32 + q * 8];
    f32x4 acc = {0.f, 0.f, 0.f, 0.f};
    acc = __builtin_amdgcn_mfma_f32_16x16x32_bf16(a0, b0, acc, 0, 0, 0);
    acc = __builtin_amdgcn_mfma_f32_16x16x32_bf16(a1, b1_, acc, 0, 0, 0);
    float bias = bproj[w * 16 + n];
#pragma unroll
    for (int r = 0; r < 4; ++r)
      yS[(q * 4 + r) * 66 + w * 16 + n] = acc[r] + bias + lacc[r] + lbias;
  }
  __syncthreads();

  // Phase D: LN1 -> residual -> LN2 (16-lane group per token, 4 ch each)
  int tokL = t >> 4;
  int ch0 = (t & 15) * 4;
  size_t tok = bN + (size_t)(h0 + (tokL >> 3)) * Ww + w0 + (tokL & 7);
  float y[4];
#pragma unroll
  for (int i = 0; i < 4; ++i) y[i] = yS[tokL * 66 + ch0 + i];
  float s = y[0] + y[1] + y[2] + y[3];
  float s2 = y[0] * y[0] + y[1] * y[1] + y[2] * y[2] + y[3] * y[3];
#pragma unroll
  for (int off = 1; off <= 8; off <<= 1) {
    s += __shfl_xor(s, off, 64);
    s2 += __shfl_xor(s2, off, 64);
  }
  float m1 = s * (1.f / 64.f);
  float rs1 = rsqrtf(s2 * (1.f / 64.f) - m1 * m1 + EPS);
  float xv[4];
  *(float4*)xv = *(const float4*)&x[tok * 64 + ch0];
  float x2v[4];
  float t_s = 0.f, t_s2 = 0.f;
#pragma unroll
  for (int i = 0; i < 4; ++i) {
    float t1 = (y[i] - m1) * rs1 * g1[ch0 + i] + b1[ch0 + i];
    x2v[i] = xv[i] + t1;
    t_s += x2v[i];
    t_s2 += x2v[i] * x2v[i];
  }
#pragma unroll
  for (int off = 1; off <= 8; off <<= 1) {
    t_s += __shfl_xor(t_s, off, 64);
    t_s2 += __shfl_xor(t_s2, off, 64);
  }
  float m2 = t_s * (1.f / 64.f);
  float rs2 = rsqrtf(t_s2 * (1.f / 64.f) - m2 * m2 + EPS);
  *(float4*)&x2[tok * 64 + ch0] = *(float4*)x2v;
  unsigned int pk[2];
  {
    float a0_ = (x2v[0] - m2) * rs2 * g2[ch0] + b2[ch0];
    float a1_ = (x2v[1] - m2) * rs2 * g2[ch0 + 1] + b2[ch0 + 1];
    float a2_ = (x2v[2] - m2) * rs2 * g2[ch0 + 2] + b2[ch0 + 2];
    float a3_ = (x2v[3] - m2) * rs2 * g2[ch0 + 3] + b2[ch0 + 3];
    pk[0] = pack2(a0_, a1_);
    pk[1] = pack2(a2_, a3_);
  }
  *(uint2*)&xn2b[tok * 64 + ch0] = *(uint2*)pk;
}

// ---------------- K5: MSFN — depthwise in regs, 1x1 via MFMA ----------------
// A/B under test this round: window loads DIRECT from global xn2b (lane=cin
// -> coalesced 128B rows, wave-uniform bounds) instead of xtS LDS staging.
// Removes 40 ds_read_u16/thread + staging loop + one __syncthreads.
__global__ __launch_bounds__(256) void k_msfn(
    const unsigned short* __restrict__ xn2b, const float* __restrict__ x2,
    const float* __restrict__ w3t, const float* __restrict__ b3,
    const float* __restrict__ w5t, const float* __restrict__ b5,
    const unsigned short* __restrict__ w1bf, const float* __restrict__ b1,
    float* __restrict__ out) {
  __shared__ __align__(16) unsigned short tsS[16 * TSP];

  int bid = blockIdx.x;
  int b = bid / 196;
  int rem = bid % 196;
  int th = rem / 7, tw = rem % 7;
  int h0 = th * 2, w0 = tw * 8;
  size_t bN = (size_t)b * Nv;
  int t = threadIdx.x;

  int cin = t & 63, tg = t >> 6;
  int tr = tg >> 1, tc0 = (tg & 1) * 4;
  float win[5][8];
  {
    const unsigned short* xb = xn2b + bN * 64 + cin;
    int gw0 = w0 - 2 + tc0;
#pragma unroll
    for (int r = 0; r < 5; ++r) {
      int gh = h0 - 2 + tr + r;
      if (gh >= 0 && gh < Hh) {
        const unsigned short* rowp = xb + ((size_t)gh * Ww + gw0) * 64;
#pragma unroll
        for (int c = 0; c < 8; ++c) {
          int gw = gw0 + c;
          win[r][c] = (gw >= 0 && gw < Ww) ? bf2f(rowp[c * 64]) : 0.0f;
        }
      } else {
#pragma unroll
        for (int c = 0; c < 8; ++c) win[r][c] = 0.0f;
      }
    }
  }

  unsigned int* tsU = (unsigned int*)tsS;
#pragma unroll 1
  for (int m2 = 0; m2 < 4; m2 += 2) {
    float a3[2][9], a5[2][25], bb3[2], bb5[2];
#pragma unroll
    for (int mm = 0; mm < 2; ++mm) {
      int m = m2 + mm;
#pragma unroll
      for (int tap = 0; tap < 9; ++tap) a3[mm][tap] = w3t[(tap * 4 + m) * 64 + cin];
#pragma unroll
      for (int tap = 0; tap < 25; ++tap) a5[mm][tap] = w5t[(tap * 4 + m) * 64 + cin];
      bb3[mm] = b3[cin * 4 + m];
      bb5[mm] = b5[cin * 4 + m];
    }
#pragma unroll
    for (int tk = 0; tk < 4; ++tk) {
      int tok = tg * 4 + tk;
      unsigned int p3 = 0, p5 = 0;
#pragma unroll
      for (int mm = 0; mm < 2; ++mm) {
        float acc3 = bb3[mm];
#pragma unroll
        for (int kh = 0; kh < 3; ++kh)
#pragma unroll
          for (int kw2 = 0; kw2 < 3; ++kw2)
            acc3 += win[1 + kh][tk + 1 + kw2] * a3[mm][kh * 3 + kw2];
        float acc5 = bb5[mm];
#pragma unroll
        for (int kh = 0; kh < 5; ++kh)
#pragma unroll
          for (int kw2 = 0; kw2 < 5; ++kw2)
            acc5 += win[kh][tk + kw2] * a5[mm][kh * 5 + kw2];
        p3 |= (unsigned int)f2bf(acc3) << (16 * mm);
        p5 |= (unsigned int)f2bf(acc5) << (16 * mm);
      }
      tsU[(tok * TSP + cin * 4 + m2) >> 1] = p3;
      tsU[(tok * TSP + 256 + cin * 4 + m2) >> 1] = p5;
    }
  }
  __syncthreads();

  int wv = tg, lane = t & 63;
  int n16 = lane & 15, quad = lane >> 4;
  const unsigned short* wrow = &w1bf[(size_t)(wv * 16 + n16) * 512];
  f32x4 acc = {0.f, 0.f, 0.f, 0.f};
#pragma unroll 4
  for (int kk = 0; kk < 16; ++kk) {
    bf16x8 af = *(const bf16x8*)&tsS[n16 * TSP + kk * 32 + quad * 8];
    bf16x8 bfr = *(const bf16x8*)&wrow[kk * 32 + quad * 8];
    acc = __builtin_amdgcn_mfma_f32_16x16x32_bf16(af, bfr, acc, 0, 0, 0);
  }
  float bias = b1[wv * 16 + n16];
#pragma unroll
  for (int r = 0; r < 4; ++r) {
    int tok = quad * 4 + r;
    int trr = tok >> 3, tcc = tok & 7;
    size_t idx = (bN + (size_t)(h0 + trr) * Ww + w0 + tcc) * 64 + wv * 16 + n16;
    out[idx] = x2[idx] + acc[r] + bias;
  }
}

extern "C" void kernel_launch(void* const* d_in, const int* in_sizes, int n_in,
                              void* d_out, int out_size, void* d_ws, size_t ws_size,
                              hipStream_t stream) {
  const float* x = (const float*)d_in[0];
  const float* n1g = (const float*)d_in[1];
  const float* n1b = (const float*)d_in[2];
  const float* wq = (const float*)d_in[3];
  const float* bq = (const float*)d_in[4];
  const float* wkv = (const float*)d_in[5];
  const float* bkv = (const float*)d_in[6];
  const float* wproj = (const float*)d_in[7];
  const float* bproj = (const float*)d_in[8];
  const float* lw = (const float*)d_in[9];
  const float* lb = (const float*)d_in[10];
  const float* n2g = (const float*)d_in[11];
  const float* n2b = (const float*)d_in[12];
  const float* w3 = (const float*)d_in[13];
  const float* b3 = (const float*)d_in[14];
  const float* w5 = (const float*)d_in[15];
  const float* b5 = (const float*)d_in[16];
  const float* w1 = (const float*)d_in[17];
  const float* b1 = (const float*)d_in[18];
  float* out = (float*)d_out;

  float* ws = (float*)d_ws;
  const size_t TOK = (size_t)Bv * Nv * Cv;  // 802816
  float* vb = ws;
  float* sumv = vb + TOK;            // 256
  float* x2 = sumv + 256;
  float* w3t = x2 + TOK;             // 2304
  float* w5t = w3t + 2304;           // 6400
  float* qkvb = w5t + 6400;          // 192
  unsigned short* q16 = (unsigned short*)(qkvb + 192);
  unsigned short* k16 = q16 + TOK;
  unsigned short* xn2b = k16 + TOK;
  unsigned short* w1bf = xn2b + TOK;       // 64*512
  unsigned short* lwb = w1bf + 64 * 512;   // 64*576
  unsigned short* wqkvt = lwb + 64 * 576;  // 192*64
  unsigned short* wprojt = wqkvt + 192 * 64;  // 64*64
  unsigned int* top8ws = (unsigned int*)(wprojt + 64 * 64 + 64);  // 12544*128 uints

  k_transpose<<<144, 256, 0, stream>>>(w1, lw, w3, w5, wq, wkv, bq, bkv, wproj,
                                       w1bf, lwb, w3t, w5t, wqkvt, qkvb, wprojt, sumv);
  k_ln_qkv<<<Bv * 196, 256, 0, stream>>>(x, n1g, n1b, wqkvt, qkvb, q16, k16, vb, sumv);
  k_attn_topk<<<Bv * 49 * 8, 128, 0, stream>>>(q16, k16, top8ws);
  k_attn_proj<<<Bv * 196, 256, 0, stream>>>(top8ws, vb, sumv, x, lwb, lb, wprojt, bproj,
                                            n1g, n1b, n2g, n2b, x2, xn2b);
  k_msfn<<<Bv * 196, 256, 0, stream>>>(xn2b, x2, w3t, b3, w5t, b5, w1bf, b1, out);
}

// Round 6
// 170.976 us; speedup vs baseline: 1.0837x; 1.0614x over previous
//
#include <hip/hip_runtime.h>
#include <math.h>

#define Bv 4
#define Nv 3136
#define Cv 64
#define Hh 56
#define Ww 56
#define HIDv 256
#define TOPKv 8
#define TSP 520   // msfn ts row pitch (bf16): dword pitch % 32 == 4 -> conflict-free b128
#define LCP 584   // im2col row pitch (576+8): same property
#define XNP 72    // ln/proj LDS bf16 row pitch (64+8): dword pitch 36 % 32 == 4
#define KSPL 16   // key splits in k_attn_topk
#define KPS 196   // keys per split (3136/16)

constexpr float SCALE = 0.125f;   // d^-0.5, d=64
constexpr float EPS = 1e-5f;
constexpr float SBIAS = 128.0f;   // score bias: all packed scores positive

typedef short bf16x8 __attribute__((ext_vector_type(8)));
typedef float f32x4 __attribute__((ext_vector_type(4)));

#define CSWAP(a, b) { unsigned int _hi = max(a, b); unsigned int _lo = min(a, b); a = _hi; b = _lo; }
// descending bitonic clean of 8 (input: bitonic), 3 stages
#define BITONIC8(T) \
  CSWAP(T[0], T[4]); CSWAP(T[1], T[5]); CSWAP(T[2], T[6]); CSWAP(T[3], T[7]); \
  CSWAP(T[0], T[2]); CSWAP(T[1], T[3]); CSWAP(T[4], T[6]); CSWAP(T[5], T[7]); \
  CSWAP(T[0], T[1]); CSWAP(T[2], T[3]); CSWAP(T[4], T[5]); CSWAP(T[6], T[7]);

__device__ __forceinline__ unsigned short f2bf(float f) {
  unsigned int u = __float_as_uint(f);
  u = (u + 0x7FFFu + ((u >> 16) & 1u)) >> 16;
  return (unsigned short)u;
}
__device__ __forceinline__ float bf2f(unsigned short u) {
  return __uint_as_float(((unsigned int)u) << 16);
}
__device__ __forceinline__ unsigned int pack2(float a, float b) {
  return (unsigned int)f2bf(a) | ((unsigned int)f2bf(b) << 16);
}

// biased-positive pack: score s is already s+SBIAS (>0), bits monotone as uint
__device__ __forceinline__ unsigned int packB(float sb, int j) {
  return (__float_as_uint(sb) & 0xFFFFF000u) | (unsigned int)j;
}

// ---------------- K0: weight prep (+ sumv zero) -----------------------------
__global__ void k_transpose(const float* __restrict__ w1, const float* __restrict__ lw,
                            const float* __restrict__ w3, const float* __restrict__ w5,
                            const float* __restrict__ wq, const float* __restrict__ wkv,
                            const float* __restrict__ bq, const float* __restrict__ bkv,
                            const float* __restrict__ wproj,
                            unsigned short* __restrict__ w1bf, unsigned short* __restrict__ lwb,
                            float* __restrict__ w3t, float* __restrict__ w5t,
                            unsigned short* __restrict__ wqkvt, float* __restrict__ qkvb,
                            unsigned short* __restrict__ wprojt, float* __restrict__ sumv) {
  int p = blockIdx.x * 256 + threadIdx.x;
  if (p < 256) sumv[p] = 0.0f;
  if (p < 64 * 512) w1bf[p] = f2bf(w1[p]);
  if (p < 64 * 576) {
    int co = p / 576, k = p % 576;
    int tap = k >> 6, ci = k & 63;
    lwb[p] = f2bf(lw[co * 576 + ci * 9 + tap]);
  }
  if (p < 36 * 64) {
    int cin = p & 63, tm = p >> 6;
    int tap = tm >> 2, m = tm & 3;
    w3t[p] = w3[(cin * 4 + m) * 9 + tap];
  }
  if (p < 100 * 64) {
    int cin = p & 63, tm = p >> 6;
    int tap = tm >> 2, m = tm & 3;
    w5t[p] = w5[(cin * 4 + m) * 25 + tap];
  }
  if (p < 192 * 64) {
    int o = p >> 6, i = p & 63;
    float v = (o < 64) ? wq[i * 64 + o] : wkv[i * 128 + (o - 64)];
    wqkvt[p] = f2bf(v);
  }
  if (p < 192) qkvb[p] = (p < 64) ? bq[p] : bkv[p - 64];
  if (p < 64 * 64) {
    int o = p >> 6, i = p & 63;
    wprojt[p] = f2bf(wproj[i * 64 + o]);
  }
}

// ---------------- K1: LN1 + QKV via MFMA (16 tokens/block) + V-sum ----------
__global__ __launch_bounds__(256) void k_ln_qkv(
    const float* __restrict__ x, const float* __restrict__ g1, const float* __restrict__ b1,
    const unsigned short* __restrict__ wqkvt, const float* __restrict__ qkvb,
    unsigned short* __restrict__ q16, unsigned short* __restrict__ k16,
    float* __restrict__ vo, float* __restrict__ sumv) {
  __shared__ __align__(16) unsigned short xnS[16 * XNP];
  int bid = blockIdx.x;
  int b = bid / 196, tile = bid % 196;
  size_t tok0 = (size_t)b * Nv + tile * 16;
  int t = threadIdx.x;
  int w = t >> 6, l = t & 63;
  int tokL = t >> 4;        // 0..15
  int ch0 = (t & 15) * 4;
  size_t tok = tok0 + tokL;
  float v[4];
  *(float4*)v = *(const float4*)&x[tok * 64 + ch0];
  float s = v[0] + v[1] + v[2] + v[3];
  float s2 = v[0] * v[0] + v[1] * v[1] + v[2] * v[2] + v[3] * v[3];
#pragma unroll
  for (int off = 1; off <= 8; off <<= 1) {
    s += __shfl_xor(s, off, 64);
    s2 += __shfl_xor(s2, off, 64);
  }
  float m = s * (1.f / 64.f);
  float rs = rsqrtf(s2 * (1.f / 64.f) - m * m + EPS);
  {
    unsigned int pk[2];
    float a0_ = (v[0] - m) * rs * g1[ch0] + b1[ch0];
    float a1_ = (v[1] - m) * rs * g1[ch0 + 1] + b1[ch0 + 1];
    float a2_ = (v[2] - m) * rs * g1[ch0 + 2] + b1[ch0 + 2];
    float a3_ = (v[3] - m) * rs * g1[ch0 + 3] + b1[ch0 + 3];
    pk[0] = pack2(a0_, a1_);
    pk[1] = pack2(a2_, a3_);
    *(uint2*)&xnS[tokL * XNP + ch0] = *(uint2*)pk;
  }
  __syncthreads();
  int n = l & 15, q = l >> 4;
  const bf16x8 a0 = *(const bf16x8*)&xnS[n * XNP + q * 8];
  const bf16x8 a1 = *(const bf16x8*)&xnS[n * XNP + 32 + q * 8];
  // Q tile j=w
  {
    const unsigned short* wr = &wqkvt[(size_t)(w * 16 + n) * 64];
    bf16x8 b0 = *(const bf16x8*)&wr[q * 8];
    bf16x8 b1_ = *(const bf16x8*)&wr[32 + q * 8];
    f32x4 acc = {0.f, 0.f, 0.f, 0.f};
    acc = __builtin_amdgcn_mfma_f32_16x16x32_bf16(a0, b0, acc, 0, 0, 0);
    acc = __builtin_amdgcn_mfma_f32_16x16x32_bf16(a1, b1_, acc, 0, 0, 0);
    float bias = qkvb[w * 16 + n];
#pragma unroll
    for (int r = 0; r < 4; ++r)
      q16[(tok0 + q * 4 + r) * 64 + w * 16 + n] = f2bf(acc[r] + bias);
  }
  // K tile j=w
  {
    const unsigned short* wr = &wqkvt[(size_t)((w + 4) * 16 + n) * 64];
    bf16x8 b0 = *(const bf16x8*)&wr[q * 8];
    bf16x8 b1_ = *(const bf16x8*)&wr[32 + q * 8];
    f32x4 acc = {0.f, 0.f, 0.f, 0.f};
    acc = __builtin_amdgcn_mfma_f32_16x16x32_bf16(a0, b0, acc, 0, 0, 0);
    acc = __builtin_amdgcn_mfma_f32_16x16x32_bf16(a1, b1_, acc, 0, 0, 0);
    float bias = qkvb[64 + w * 16 + n];
#pragma unroll
    for (int r = 0; r < 4; ++r)
      k16[(tok0 + q * 4 + r) * 64 + w * 16 + n] = f2bf(acc[r] + bias);
  }
  // V tile j=w + fused per-batch column sum
  {
    const unsigned short* wr = &wqkvt[(size_t)((w + 8) * 16 + n) * 64];
    bf16x8 b0 = *(const bf16x8*)&wr[q * 8];
    bf16x8 b1_ = *(const bf16x8*)&wr[32 + q * 8];
    f32x4 acc = {0.f, 0.f, 0.f, 0.f};
    acc = __builtin_amdgcn_mfma_f32_16x16x32_bf16(a0, b0, acc, 0, 0, 0);
    acc = __builtin_amdgcn_mfma_f32_16x16x32_bf16(a1, b1_, acc, 0, 0, 0);
    float bias = qkvb[128 + w * 16 + n];
    float vp = acc[0] + acc[1] + acc[2] + acc[3] + 4.0f * bias;
#pragma unroll
    for (int r = 0; r < 4; ++r)
      vo[(tok0 + q * 4 + r) * 64 + w * 16 + n] = acc[r] + bias;
    vp += __shfl_xor(vp, 16, 64);
    vp += __shfl_xor(vp, 32, 64);
    if (q == 0) atomicAdd(&sumv[b * 64 + w * 16 + n], vp);
  }
}

// ---------------- K2a: LDS-staged-K 4-tile top-8 (16 key splits) ------------
// block=128 = 2 waves sharing ONE split (different tilegroups). The split's
// K (208 rows x 128B, rows 196..207 are masked tail) is staged once into
// LDS with an XOR swizzle (slot ^= row&7) so the stride-128B ds_read_b128
// pattern is bank-spread (G4). Inner loop reads LDS (short latency, no
// global stalls); global K traffic halves vs per-wave streaming. Candidate
// packing/klim masking identical to the global version -> bit-exact top-8.
#define PAIRMERGE(T, accA, accB, jb) { \
    unsigned int _p0 = packB(accA[0], (jb) + 0); \
    unsigned int _p1 = packB(accA[1], (jb) + 1); \
    unsigned int _p2 = packB(accA[2], (jb) + 2); \
    unsigned int _p3 = packB(accA[3], (jb) + 3); \
    unsigned int _q0 = packB(accB[0], (jb) + 16); \
    unsigned int _q1 = packB(accB[1], (jb) + 17); \
    unsigned int _q2 = packB(accB[2], (jb) + 18); \
    unsigned int _q3 = packB(accB[3], (jb) + 19); \
    CSWAP(_p0, _p1); CSWAP(_p2, _p3); CSWAP(_p0, _p2); CSWAP(_p1, _p3); CSWAP(_p1, _p2); \
    CSWAP(_q0, _q1); CSWAP(_q2, _q3); CSWAP(_q0, _q2); CSWAP(_q1, _q3); CSWAP(_q1, _q2); \
    unsigned int _u8[8] = {_p0, _p1, _p2, _p3, _q3, _q2, _q1, _q0}; \
    BITONIC8(_u8); \
    T[0] = max(T[0], _u8[7]); \
    T[1] = max(T[1], _u8[6]); \
    T[2] = max(T[2], _u8[5]); \
    T[3] = max(T[3], _u8[4]); \
    T[4] = max(T[4], _u8[3]); \
    T[5] = max(T[5], _u8[2]); \
    T[6] = max(T[6], _u8[1]); \
    T[7] = max(T[7], _u8[0]); \
    BITONIC8(T); }

__global__ __launch_bounds__(128, 3) void k_attn_topk(
    const unsigned short* __restrict__ q16, const unsigned short* __restrict__ k16,
    unsigned int* __restrict__ top8out) {
  __shared__ __align__(16) unsigned short kS[13312];  // 26624 B = 208 rows x 128B (swizzled)
  int bid = blockIdx.x;
  int t = threadIdx.x;
  int w = t >> 6;
  int lane = t & 63;
  int tgp = bid % 25;
  int bs = bid / 25;              // 0..63
  int b = bs >> 4, split = bs & 15;
  int tg = tgp * 2 + w;           // 0..49 (49 = idle wave)
  size_t bN = (size_t)b * Nv;
  int kbase = split * KPS;        // KPS=196

  // cooperative staging: 13 rounds x 128 threads x 16B; linear src, swizzled dst.
  // dst row = t>>3 (+16/round), slot = (t&7) ^ (row&7); row&7 invariant per round.
  {
    const char* src = (const char*)(k16 + bN * 64) + kbase * 128 + t * 16;
    char* dst = (char*)kS + (t >> 3) * 128 + (((t & 7) ^ ((t >> 3) & 7)) << 4);
#pragma unroll
    for (int r = 0; r < 13; ++r)
      *(uint4*)(dst + r * 2048) = *(const uint4*)(src + r * 2048);
  }
  __syncthreads();
  if (tg >= 49) return;

  int qbase = b * Nv + tg * 64;
  int qcol = lane & 15, quad = lane >> 4;
  int quad4 = quad * 4;
  int m = lane & 15;

  bf16x8 qf0a[4], qf1a[4];
#pragma unroll
  for (int tt = 0; tt < 4; ++tt) {
    qf0a[tt] = *(const bf16x8*)&q16[((size_t)(qbase + tt * 16 + qcol)) * 64 + quad * 8];
    qf1a[tt] = *(const bf16x8*)&q16[((size_t)(qbase + tt * 16 + qcol)) * 64 + 32 + quad * 8];
  }

  unsigned int t8[4][8];
#pragma unroll
  for (int tt = 0; tt < 4; ++tt)
#pragma unroll
    for (int u = 0; u < 8; ++u) t8[tt][u] = 0u;

  int jbA = kbase + quad4;
  // per-lane swizzled LDS pointers: row = m (+16/chunk), slots quad / quad+4
  int swz = m & 7;
  const char* pa = (const char*)kS + m * 128 + ((quad ^ swz) << 4);
  const char* pb = (const char*)kS + m * 128 + (((quad + 4) ^ swz) << 4);

#pragma unroll 1
  for (int it = 0; it < 6; ++it) {  // chunk pairs 0..5 = keys 0..191
    bf16x8 ca0 = *(const bf16x8*)(pa + it * 4096);
    bf16x8 ca1 = *(const bf16x8*)(pb + it * 4096);
    bf16x8 cb0 = *(const bf16x8*)(pa + it * 4096 + 2048);
    bf16x8 cb1 = *(const bf16x8*)(pb + it * 4096 + 2048);

#pragma unroll
    for (int tt = 0; tt < 4; ++tt) {
      f32x4 accA = {SBIAS, SBIAS, SBIAS, SBIAS};
      accA = __builtin_amdgcn_mfma_f32_16x16x32_bf16(ca0, qf0a[tt], accA, 0, 0, 0);
      accA = __builtin_amdgcn_mfma_f32_16x16x32_bf16(ca1, qf1a[tt], accA, 0, 0, 0);
      f32x4 accB = {SBIAS, SBIAS, SBIAS, SBIAS};
      accB = __builtin_amdgcn_mfma_f32_16x16x32_bf16(cb0, qf0a[tt], accB, 0, 0, 0);
      accB = __builtin_amdgcn_mfma_f32_16x16x32_bf16(cb1, qf1a[tt], accB, 0, 0, 0);
      PAIRMERGE(t8[tt], accA, accB, jbA);
    }
    jbA += 32;
  }

  {  // ragged chunk 12: rows 192..207 staged, keys 192..195 valid (klim mask)
    bf16x8 ka0 = *(const bf16x8*)(pa + 12 * 2048);
    bf16x8 ka1 = *(const bf16x8*)(pb + 12 * 2048);
    int klim = kbase + KPS;
#pragma unroll
    for (int tt = 0; tt < 4; ++tt) {
      f32x4 accA = {SBIAS, SBIAS, SBIAS, SBIAS};
      accA = __builtin_amdgcn_mfma_f32_16x16x32_bf16(ka0, qf0a[tt], accA, 0, 0, 0);
      accA = __builtin_amdgcn_mfma_f32_16x16x32_bf16(ka1, qf1a[tt], accA, 0, 0, 0);
      unsigned int p0 = (jbA + 0 < klim) ? packB(accA[0], jbA + 0) : 0u;
      unsigned int p1 = (jbA + 1 < klim) ? packB(accA[1], jbA + 1) : 0u;
      unsigned int p2 = (jbA + 2 < klim) ? packB(accA[2], jbA + 2) : 0u;
      unsigned int p3 = (jbA + 3 < klim) ? packB(accA[3], jbA + 3) : 0u;
      CSWAP(p0, p1); CSWAP(p2, p3); CSWAP(p0, p2); CSWAP(p1, p3); CSWAP(p1, p2);
      t8[tt][4] = max(t8[tt][4], p3);
      t8[tt][5] = max(t8[tt][5], p2);
      t8[tt][6] = max(t8[tt][6], p1);
      t8[tt][7] = max(t8[tt][7], p0);
      BITONIC8(t8[tt]);
    }
  }

  // merge across quads (same query col): butterfly xor 16, 32 — per tile
#pragma unroll
  for (int tt = 0; tt < 4; ++tt) {
#pragma unroll
    for (int step = 16; step <= 32; step <<= 1) {
      unsigned int o[8];
#pragma unroll
      for (int i = 0; i < 8; ++i) o[i] = (unsigned int)__shfl_xor((int)t8[tt][i], step, 64);
      unsigned int nw[8];
#pragma unroll
      for (int i = 0; i < 8; ++i) nw[i] = max(t8[tt][i], o[7 - i]);
#pragma unroll
      for (int i = 0; i < 8; ++i) t8[tt][i] = nw[i];
      BITONIC8(t8[tt]);
    }
    if (quad == 0) {
      size_t obase = ((size_t)(bN + tg * 64 + tt * 16 + qcol)) * 128 + split * 8;
      *(uint4*)&top8out[obase] = make_uint4(t8[tt][0], t8[tt][1], t8[tt][2], t8[tt][3]);
      *(uint4*)&top8out[obase + 4] = make_uint4(t8[tt][4], t8[tt][5], t8[tt][6], t8[tt][7]);
    }
  }
}

// ---- K2b: 16-list merge + PV + local-conv(fused) + proj + LN1 + res + LN2 --
// Phase A runs on wave 0 (4 lanes/token x 4 lists + 2-step butterfly),
// OVERLAPPED with im2col staging on waves 1-3. Phase B's 32 scattered vg
// gathers are issued before the conv MFMA loop so their latency hides.
__global__ __launch_bounds__(256) void k_attn_proj(
    const unsigned int* __restrict__ top8, const float* __restrict__ vg,
    const float* __restrict__ sumv, const float* __restrict__ x,
    const unsigned short* __restrict__ lwb, const float* __restrict__ lb,
    const unsigned short* __restrict__ wprojt, const float* __restrict__ bproj,
    const float* __restrict__ g1, const float* __restrict__ b1,
    const float* __restrict__ g2, const float* __restrict__ b2,
    float* __restrict__ x2, unsigned short* __restrict__ xn2b) {
  __shared__ float kwS[16][8];
  __shared__ int kidxS[16][8];
  __shared__ float invZS[16];
  __shared__ __align__(16) unsigned short imS[16 * LCP];
  __shared__ __align__(16) unsigned short gS[16 * XNP];
  __shared__ float yS[16 * 66];
  int bid = blockIdx.x;
  int b = bid / 196, rem = bid % 196;
  int th = rem / 7, tw = rem % 7;
  int h0 = th * 2, w0 = tw * 8;
  size_t bN = (size_t)b * Nv;
  int t = threadIdx.x;

  if (t < 64) {
    // Phase A (wave 0): parallel 16-list merge. lane group la=t&3 merges
    // lists 4*la..4*la+3 for token tk=t>>2, then butterfly xor 1,2.
    int tk = t >> 2, la = t & 3;
    int gtok = (h0 + (tk >> 3)) * Ww + w0 + (tk & 7);
    size_t base = (bN + gtok) * 128 + la * 32;
    unsigned int A[8];
#pragma unroll
    for (int i = 0; i < 8; ++i) A[i] = top8[base + i];
#pragma unroll
    for (int h = 1; h < 4; ++h) {
      unsigned int Bb[8];
#pragma unroll
      for (int i = 0; i < 8; ++i) Bb[i] = top8[base + h * 8 + i];
#pragma unroll
      for (int i = 0; i < 8; ++i) A[i] = max(A[i], Bb[7 - i]);
      BITONIC8(A);
    }
#pragma unroll
    for (int step = 1; step <= 2; step <<= 1) {
      unsigned int o[8];
#pragma unroll
      for (int i = 0; i < 8; ++i) o[i] = (unsigned int)__shfl_xor((int)A[i], step, 64);
#pragma unroll
      for (int i = 0; i < 8; ++i) A[i] = max(A[i], o[7 - i]);
      BITONIC8(A);
    }
    if (la == 0) {
      float Z = (float)(Nv - TOPKv);
#pragma unroll
      for (int u = 0; u < 8; ++u) {
        float sb = __uint_as_float(A[u] & 0xFFFFF000u);
        float s = (sb - SBIAS) * SCALE;
        float e = __expf(s);
        kwS[tk][u] = e - 1.0f;
        kidxS[tk][u] = (int)(A[u] & 0xFFFu);
        Z += e;
      }
      invZS[tk] = 1.0f / Z;
    }
  } else {
    // im2col staging from fp32 x (bf16 inline), waves 1-3: 1152/192 = 6 rounds
    for (int p = t - 64; p < 1152; p += 192) {
      int sub = p & 7, s = p >> 3;
      int tok = s / 9, tap = s % 9;
      int tr = tok >> 3, tc = tok & 7;
      int dh = tap / 3, dw = tap % 3;
      int gh = h0 + tr - 1 + dh, gw = w0 + tc - 1 + dw;
      uint4 uu = {0u, 0u, 0u, 0u};
      if (gh >= 0 && gh < Hh && gw >= 0 && gw < Ww) {
        const float* xp = &x[(bN + gh * Ww + gw) * 64 + sub * 8];
        float4 va = *(const float4*)xp;
        float4 vb = *(const float4*)(xp + 4);
        uu.x = pack2(va.x, va.y);
        uu.y = pack2(va.z, va.w);
        uu.z = pack2(vb.x, vb.y);
        uu.w = pack2(vb.z, vb.w);
      }
      *(uint4*)&imS[tok * LCP + tap * 64 + sub * 8] = uu;
    }
  }
  __syncthreads();

  int w = t >> 6, l = t & 63;
  int n = l & 15, q = l >> 4;

  // Phase B part 1: issue the 32 scattered vg gathers (latency hides under conv)
  int c = t & 63, rg = t >> 6;
  float vgv[4][8];
#pragma unroll
  for (int rr = 0; rr < 4; ++rr) {
    int tokL = rg * 4 + rr;
#pragma unroll
    for (int u = 0; u < 8; ++u)
      vgv[rr][u] = vg[(bN + kidxS[tokL][u]) * 64 + c];
  }

  // local conv MFMA (18 per wave), result in registers
  f32x4 lacc = {0.f, 0.f, 0.f, 0.f};
  {
    const unsigned short* lwrow = &lwb[(size_t)(w * 16 + n) * 576];
#pragma unroll 6
    for (int kk = 0; kk < 18; ++kk) {
      bf16x8 af = *(const bf16x8*)&imS[n * LCP + kk * 32 + q * 8];
      bf16x8 bfr = *(const bf16x8*)&lwrow[kk * 32 + q * 8];
      lacc = __builtin_amdgcn_mfma_f32_16x16x32_bf16(af, bfr, lacc, 0, 0, 0);
    }
  }
  float lbias = lb[w * 16 + n];

  // Phase B part 2: g = (sumv + sum_top8 (e^s-1) v)/Z -> gS (bf16)
  {
    float sv = sumv[b * 64 + c];
#pragma unroll
    for (int rr = 0; rr < 4; ++rr) {
      int tokL = rg * 4 + rr;
      float acc = sv;
#pragma unroll
      for (int u = 0; u < 8; ++u)
        acc += kwS[tokL][u] * vgv[rr][u];
      gS[tokL * XNP + c] = f2bf(acc * invZS[tokL]);
    }
  }
  __syncthreads();

  // Phase C: proj GEMM + add local conv, y -> yS
  {
    const bf16x8 a0 = *(const bf16x8*)&gS[n * XNP + q * 8];
    const bf16x8 a1 = *(const bf16x8*)&gS[n * XNP + 32 + q * 8];
    const unsigned short* wr = &wprojt[(size_t)(w * 16 + n) * 64];
    bf16x8 b0 = *(const bf16x8*)&wr[q * 8];
    bf16x8 b1_ = *(const bf16x8*)&wr[32 + q * 8];
    f32x4 acc = {0.f, 0.f, 0.f, 0.f};
    acc = __builtin_amdgcn_mfma_f32_16x16x32_bf16(a0, b0, acc, 0, 0, 0);
    acc = __builtin_amdgcn_mfma_f32_16x16x32_bf16(a1, b1_, acc, 0, 0, 0);
    float bias = bproj[w * 16 + n];
#pragma unroll
    for (int r = 0; r < 4; ++r)
      yS[(q * 4 + r) * 66 + w * 16 + n] = acc[r] + bias + lacc[r] + lbias;
  }
  __syncthreads();

  // Phase D: LN1 -> residual -> LN2 (16-lane group per token, 4 ch each)
  int tokL = t >> 4;
  int ch0 = (t & 15) * 4;
  size_t tok = bN + (size_t)(h0 + (tokL >> 3)) * Ww + w0 + (tokL & 7);
  float y[4];
#pragma unroll
  for (int i = 0; i < 4; ++i) y[i] = yS[tokL * 66 + ch0 + i];
  float s = y[0] + y[1] + y[2] + y[3];
  float s2 = y[0] * y[0] + y[1] * y[1] + y[2] * y[2] + y[3] * y[3];
#pragma unroll
  for (int off = 1; off <= 8; off <<= 1) {
    s += __shfl_xor(s, off, 64);
    s2 += __shfl_xor(s2, off, 64);
  }
  float m1 = s * (1.f / 64.f);
  float rs1 = rsqrtf(s2 * (1.f / 64.f) - m1 * m1 + EPS);
  float xv[4];
  *(float4*)xv = *(const float4*)&x[tok * 64 + ch0];
  float x2v[4];
  float t_s = 0.f, t_s2 = 0.f;
#pragma unroll
  for (int i = 0; i < 4; ++i) {
    float t1 = (y[i] - m1) * rs1 * g1[ch0 + i] + b1[ch0 + i];
    x2v[i] = xv[i] + t1;
    t_s += x2v[i];
    t_s2 += x2v[i] * x2v[i];
  }
#pragma unroll
  for (int off = 1; off <= 8; off <<= 1) {
    t_s += __shfl_xor(t_s, off, 64);
    t_s2 += __shfl_xor(t_s2, off, 64);
  }
  float m2 = t_s * (1.f / 64.f);
  float rs2 = rsqrtf(t_s2 * (1.f / 64.f) - m2 * m2 + EPS);
  *(float4*)&x2[tok * 64 + ch0] = *(float4*)x2v;
  unsigned int pk[2];
  {
    float a0_ = (x2v[0] - m2) * rs2 * g2[ch0] + b2[ch0];
    float a1_ = (x2v[1] - m2) * rs2 * g2[ch0 + 1] + b2[ch0 + 1];
    float a2_ = (x2v[2] - m2) * rs2 * g2[ch0 + 2] + b2[ch0 + 2];
    float a3_ = (x2v[3] - m2) * rs2 * g2[ch0 + 3] + b2[ch0 + 3];
    pk[0] = pack2(a0_, a1_);
    pk[1] = pack2(a2_, a3_);
  }
  *(uint2*)&xn2b[tok * 64 + ch0] = *(uint2*)pk;
}

// ---------------- K5: MSFN — depthwise in regs, 1x1 via MFMA ----------------
// REVERTED to xtS LDS staging (R3): direct-global window loads cost +10us
// (R5 A/B) — staging reads the 6x12 halo once and reuses it across all 4
// wave-groups; direct re-reads overlapping windows 2.2x with exposed latency.
__global__ __launch_bounds__(256) void k_msfn(
    const unsigned short* __restrict__ xn2b, const float* __restrict__ x2,
    const float* __restrict__ w3t, const float* __restrict__ b3,
    const float* __restrict__ w5t, const float* __restrict__ b5,
    const unsigned short* __restrict__ w1bf, const float* __restrict__ b1,
    float* __restrict__ out) {
  __shared__ __align__(16) unsigned short xtS[6 * 12 * 64];
  __shared__ __align__(16) unsigned short tsS[16 * TSP];

  int bid = blockIdx.x;
  int b = bid / 196;
  int rem = bid % 196;
  int th = rem / 7, tw = rem % 7;
  int h0 = th * 2, w0 = tw * 8;
  size_t bN = (size_t)b * Nv;
  int t = threadIdx.x;

  unsigned int* xtU = (unsigned int*)xtS;
  for (int p = t; p < 6 * 12 * 32; p += 256) {
    int cp = p & 31, rc = p >> 5;
    int r = rc / 12, cc = rc % 12;
    int gh = h0 - 2 + r, gw = w0 - 2 + cc;
    unsigned int v = 0;
    if (gh >= 0 && gh < Hh && gw >= 0 && gw < Ww)
      v = *(const unsigned int*)&xn2b[(bN + gh * Ww + gw) * 64 + cp * 2];
    xtU[rc * 32 + cp] = v;
  }
  __syncthreads();

  int cin = t & 63, tg = t >> 6;
  int tr = tg >> 1, tc0 = (tg & 1) * 4;
  float win[5][8];
#pragma unroll
  for (int r = 0; r < 5; ++r)
#pragma unroll
    for (int c = 0; c < 8; ++c)
      win[r][c] = bf2f(xtS[((tr + r) * 12 + tc0 + c) * 64 + cin]);

  unsigned int* tsU = (unsigned int*)tsS;
#pragma unroll 1
  for (int m2 = 0; m2 < 4; m2 += 2) {
    float a3[2][9], a5[2][25], bb3[2], bb5[2];
#pragma unroll
    for (int mm = 0; mm < 2; ++mm) {
      int m = m2 + mm;
#pragma unroll
      for (int tap = 0; tap < 9; ++tap) a3[mm][tap] = w3t[(tap * 4 + m) * 64 + cin];
#pragma unroll
      for (int tap = 0; tap < 25; ++tap) a5[mm][tap] = w5t[(tap * 4 + m) * 64 + cin];
      bb3[mm] = b3[cin * 4 + m];
      bb5[mm] = b5[cin * 4 + m];
    }
#pragma unroll
    for (int tk = 0; tk < 4; ++tk) {
      int tok = tg * 4 + tk;
      unsigned int p3 = 0, p5 = 0;
#pragma unroll
      for (int mm = 0; mm < 2; ++mm) {
        float acc3 = bb3[mm];
#pragma unroll
        for (int kh = 0; kh < 3; ++kh)
#pragma unroll
          for (int kw2 = 0; kw2 < 3; ++kw2)
            acc3 += win[1 + kh][tk + 1 + kw2] * a3[mm][kh * 3 + kw2];
        float acc5 = bb5[mm];
#pragma unroll
        for (int kh = 0; kh < 5; ++kh)
#pragma unroll
          for (int kw2 = 0; kw2 < 5; ++kw2)
            acc5 += win[kh][tk + kw2] * a5[mm][kh * 5 + kw2];
        p3 |= (unsigned int)f2bf(acc3) << (16 * mm);
        p5 |= (unsigned int)f2bf(acc5) << (16 * mm);
      }
      tsU[(tok * TSP + cin * 4 + m2) >> 1] = p3;
      tsU[(tok * TSP + 256 + cin * 4 + m2) >> 1] = p5;
    }
  }
  __syncthreads();

  int wv = tg, lane = t & 63;
  int n16 = lane & 15, quad = lane >> 4;
  const unsigned short* wrow = &w1bf[(size_t)(wv * 16 + n16) * 512];
  f32x4 acc = {0.f, 0.f, 0.f, 0.f};
#pragma unroll 4
  for (int kk = 0; kk < 16; ++kk) {
    bf16x8 af = *(const bf16x8*)&tsS[n16 * TSP + kk * 32 + quad * 8];
    bf16x8 bfr = *(const bf16x8*)&wrow[kk * 32 + quad * 8];
    acc = __builtin_amdgcn_mfma_f32_16x16x32_bf16(af, bfr, acc, 0, 0, 0);
  }
  float bias = b1[wv * 16 + n16];
#pragma unroll
  for (int r = 0; r < 4; ++r) {
    int tok = quad * 4 + r;
    int trr = tok >> 3, tcc = tok & 7;
    size_t idx = (bN + (size_t)(h0 + trr) * Ww + w0 + tcc) * 64 + wv * 16 + n16;
    out[idx] = x2[idx] + acc[r] + bias;
  }
}

extern "C" void kernel_launch(void* const* d_in, const int* in_sizes, int n_in,
                              void* d_out, int out_size, void* d_ws, size_t ws_size,
                              hipStream_t stream) {
  const float* x = (const float*)d_in[0];
  const float* n1g = (const float*)d_in[1];
  const float* n1b = (const float*)d_in[2];
  const float* wq = (const float*)d_in[3];
  const float* bq = (const float*)d_in[4];
  const float* wkv = (const float*)d_in[5];
  const float* bkv = (const float*)d_in[6];
  const float* wproj = (const float*)d_in[7];
  const float* bproj = (const float*)d_in[8];
  const float* lw = (const float*)d_in[9];
  const float* lb = (const float*)d_in[10];
  const float* n2g = (const float*)d_in[11];
  const float* n2b = (const float*)d_in[12];
  const float* w3 = (const float*)d_in[13];
  const float* b3 = (const float*)d_in[14];
  const float* w5 = (const float*)d_in[15];
  const float* b5 = (const float*)d_in[16];
  const float* w1 = (const float*)d_in[17];
  const float* b1 = (const float*)d_in[18];
  float* out = (float*)d_out;

  float* ws = (float*)d_ws;
  const size_t TOK = (size_t)Bv * Nv * Cv;  // 802816
  float* vb = ws;
  float* sumv = vb + TOK;            // 256
  float* x2 = sumv + 256;
  float* w3t = x2 + TOK;             // 2304
  float* w5t = w3t + 2304;           // 6400
  float* qkvb = w5t + 6400;          // 192
  unsigned short* q16 = (unsigned short*)(qkvb + 192);
  unsigned short* k16 = q16 + TOK;
  unsigned short* xn2b = k16 + TOK;
  unsigned short* w1bf = xn2b + TOK;       // 64*512
  unsigned short* lwb = w1bf + 64 * 512;   // 64*576
  unsigned short* wqkvt = lwb + 64 * 576;  // 192*64
  unsigned short* wprojt = wqkvt + 192 * 64;  // 64*64
  unsigned int* top8ws = (unsigned int*)(wprojt + 64 * 64 + 64);  // 12544*128 uints

  k_transpose<<<144, 256, 0, stream>>>(w1, lw, w3, w5, wq, wkv, bq, bkv, wproj,
                                       w1bf, lwb, w3t, w5t, wqkvt, qkvb, wprojt, sumv);
  k_ln_qkv<<<Bv * 196, 256, 0, stream>>>(x, n1g, n1b, wqkvt, qkvb, q16, k16, vb, sumv);
  k_attn_topk<<<Bv * 16 * 25, 128, 0, stream>>>(q16, k16, top8ws);
  k_attn_proj<<<Bv * 196, 256, 0, stream>>>(top8ws, vb, sumv, x, lwb, lb, wprojt, bproj,
                                            n1g, n1b, n2g, n2b, x2, xn2b);
  k_msfn<<<Bv * 196, 256, 0, stream>>>(xn2b, x2, w3t, b3, w5t, b5, w1bf, b1, out);
}

// Round 7
// 167.753 us; speedup vs baseline: 1.1045x; 1.0192x over previous
//
#include <hip/hip_runtime.h>
#include <math.h>

#define Bv 4
#define Nv 3136
#define Cv 64
#define Hh 56
#define Ww 56
#define HIDv 256
#define TOPKv 8
#define TSP 520   // msfn ts row pitch (bf16): dword pitch % 32 == 4 -> conflict-free b128
#define LCP 584   // im2col row pitch (576+8): same property
#define XNP 72    // ln/proj LDS bf16 row pitch (64+8): dword pitch 36 % 32 == 4
#define KSPL 16   // key splits in k_attn_topk
#define KPS 196   // keys per split (3136/16)

constexpr float SCALE = 0.125f;   // d^-0.5, d=64
constexpr float EPS = 1e-5f;
constexpr float SBIAS = 128.0f;   // score bias: all packed scores positive

typedef short bf16x8 __attribute__((ext_vector_type(8)));
typedef float f32x4 __attribute__((ext_vector_type(4)));

#define CSWAP(a, b) { unsigned int _hi = max(a, b); unsigned int _lo = min(a, b); a = _hi; b = _lo; }
// descending bitonic clean of 8 (input: bitonic), 3 stages
#define BITONIC8(T) \
  CSWAP(T[0], T[4]); CSWAP(T[1], T[5]); CSWAP(T[2], T[6]); CSWAP(T[3], T[7]); \
  CSWAP(T[0], T[2]); CSWAP(T[1], T[3]); CSWAP(T[4], T[6]); CSWAP(T[5], T[7]); \
  CSWAP(T[0], T[1]); CSWAP(T[2], T[3]); CSWAP(T[4], T[5]); CSWAP(T[6], T[7]);

__device__ __forceinline__ unsigned short f2bf(float f) {
  unsigned int u = __float_as_uint(f);
  u = (u + 0x7FFFu + ((u >> 16) & 1u)) >> 16;
  return (unsigned short)u;
}
__device__ __forceinline__ float bf2f(unsigned short u) {
  return __uint_as_float(((unsigned int)u) << 16);
}
__device__ __forceinline__ unsigned int pack2(float a, float b) {
  return (unsigned int)f2bf(a) | ((unsigned int)f2bf(b) << 16);
}

// biased-positive pack: score s is already s+SBIAS (>0), bits monotone as uint
__device__ __forceinline__ unsigned int packB(float sb, int j) {
  return (__float_as_uint(sb) & 0xFFFFF000u) | (unsigned int)j;
}

// ---------------- K0: weight prep (+ sumv zero) -----------------------------
__global__ void k_transpose(const float* __restrict__ w1, const float* __restrict__ lw,
                            const float* __restrict__ w3, const float* __restrict__ w5,
                            const float* __restrict__ wq, const float* __restrict__ wkv,
                            const float* __restrict__ bq, const float* __restrict__ bkv,
                            const float* __restrict__ wproj,
                            unsigned short* __restrict__ w1bf, unsigned short* __restrict__ lwb,
                            float* __restrict__ w3t, float* __restrict__ w5t,
                            unsigned short* __restrict__ wqkvt, float* __restrict__ qkvb,
                            unsigned short* __restrict__ wprojt, float* __restrict__ sumv) {
  int p = blockIdx.x * 256 + threadIdx.x;
  if (p < 256) sumv[p] = 0.0f;
  if (p < 64 * 512) w1bf[p] = f2bf(w1[p]);
  if (p < 64 * 576) {
    int co = p / 576, k = p % 576;
    int tap = k >> 6, ci = k & 63;
    lwb[p] = f2bf(lw[co * 576 + ci * 9 + tap]);
  }
  if (p < 36 * 64) {
    int cin = p & 63, tm = p >> 6;
    int tap = tm >> 2, m = tm & 3;
    w3t[p] = w3[(cin * 4 + m) * 9 + tap];
  }
  if (p < 100 * 64) {
    int cin = p & 63, tm = p >> 6;
    int tap = tm >> 2, m = tm & 3;
    w5t[p] = w5[(cin * 4 + m) * 25 + tap];
  }
  if (p < 192 * 64) {
    int o = p >> 6, i = p & 63;
    float v = (o < 64) ? wq[i * 64 + o] : wkv[i * 128 + (o - 64)];
    wqkvt[p] = f2bf(v);
  }
  if (p < 192) qkvb[p] = (p < 64) ? bq[p] : bkv[p - 64];
  if (p < 64 * 64) {
    int o = p >> 6, i = p & 63;
    wprojt[p] = f2bf(wproj[i * 64 + o]);
  }
}

// ---------------- K1: LN1 + QKV via MFMA (16 tokens/block) + V-sum ----------
__global__ __launch_bounds__(256) void k_ln_qkv(
    const float* __restrict__ x, const float* __restrict__ g1, const float* __restrict__ b1,
    const unsigned short* __restrict__ wqkvt, const float* __restrict__ qkvb,
    unsigned short* __restrict__ q16, unsigned short* __restrict__ k16,
    float* __restrict__ vo, float* __restrict__ sumv) {
  __shared__ __align__(16) unsigned short xnS[16 * XNP];
  int bid = blockIdx.x;
  int b = bid / 196, tile = bid % 196;
  size_t tok0 = (size_t)b * Nv + tile * 16;
  int t = threadIdx.x;
  int w = t >> 6, l = t & 63;
  int tokL = t >> 4;        // 0..15
  int ch0 = (t & 15) * 4;
  size_t tok = tok0 + tokL;
  float v[4];
  *(float4*)v = *(const float4*)&x[tok * 64 + ch0];
  float s = v[0] + v[1] + v[2] + v[3];
  float s2 = v[0] * v[0] + v[1] * v[1] + v[2] * v[2] + v[3] * v[3];
#pragma unroll
  for (int off = 1; off <= 8; off <<= 1) {
    s += __shfl_xor(s, off, 64);
    s2 += __shfl_xor(s2, off, 64);
  }
  float m = s * (1.f / 64.f);
  float rs = rsqrtf(s2 * (1.f / 64.f) - m * m + EPS);
  {
    unsigned int pk[2];
    float a0_ = (v[0] - m) * rs * g1[ch0] + b1[ch0];
    float a1_ = (v[1] - m) * rs * g1[ch0 + 1] + b1[ch0 + 1];
    float a2_ = (v[2] - m) * rs * g1[ch0 + 2] + b1[ch0 + 2];
    float a3_ = (v[3] - m) * rs * g1[ch0 + 3] + b1[ch0 + 3];
    pk[0] = pack2(a0_, a1_);
    pk[1] = pack2(a2_, a3_);
    *(uint2*)&xnS[tokL * XNP + ch0] = *(uint2*)pk;
  }
  __syncthreads();
  int n = l & 15, q = l >> 4;
  const bf16x8 a0 = *(const bf16x8*)&xnS[n * XNP + q * 8];
  const bf16x8 a1 = *(const bf16x8*)&xnS[n * XNP + 32 + q * 8];
  // Q tile j=w
  {
    const unsigned short* wr = &wqkvt[(size_t)(w * 16 + n) * 64];
    bf16x8 b0 = *(const bf16x8*)&wr[q * 8];
    bf16x8 b1_ = *(const bf16x8*)&wr[32 + q * 8];
    f32x4 acc = {0.f, 0.f, 0.f, 0.f};
    acc = __builtin_amdgcn_mfma_f32_16x16x32_bf16(a0, b0, acc, 0, 0, 0);
    acc = __builtin_amdgcn_mfma_f32_16x16x32_bf16(a1, b1_, acc, 0, 0, 0);
    float bias = qkvb[w * 16 + n];
#pragma unroll
    for (int r = 0; r < 4; ++r)
      q16[(tok0 + q * 4 + r) * 64 + w * 16 + n] = f2bf(acc[r] + bias);
  }
  // K tile j=w
  {
    const unsigned short* wr = &wqkvt[(size_t)((w + 4) * 16 + n) * 64];
    bf16x8 b0 = *(const bf16x8*)&wr[q * 8];
    bf16x8 b1_ = *(const bf16x8*)&wr[32 + q * 8];
    f32x4 acc = {0.f, 0.f, 0.f, 0.f};
    acc = __builtin_amdgcn_mfma_f32_16x16x32_bf16(a0, b0, acc, 0, 0, 0);
    acc = __builtin_amdgcn_mfma_f32_16x16x32_bf16(a1, b1_, acc, 0, 0, 0);
    float bias = qkvb[64 + w * 16 + n];
#pragma unroll
    for (int r = 0; r < 4; ++r)
      k16[(tok0 + q * 4 + r) * 64 + w * 16 + n] = f2bf(acc[r] + bias);
  }
  // V tile j=w + fused per-batch column sum
  {
    const unsigned short* wr = &wqkvt[(size_t)((w + 8) * 16 + n) * 64];
    bf16x8 b0 = *(const bf16x8*)&wr[q * 8];
    bf16x8 b1_ = *(const bf16x8*)&wr[32 + q * 8];
    f32x4 acc = {0.f, 0.f, 0.f, 0.f};
    acc = __builtin_amdgcn_mfma_f32_16x16x32_bf16(a0, b0, acc, 0, 0, 0);
    acc = __builtin_amdgcn_mfma_f32_16x16x32_bf16(a1, b1_, acc, 0, 0, 0);
    float bias = qkvb[128 + w * 16 + n];
    float vp = acc[0] + acc[1] + acc[2] + acc[3] + 4.0f * bias;
#pragma unroll
    for (int r = 0; r < 4; ++r)
      vo[(tok0 + q * 4 + r) * 64 + w * 16 + n] = acc[r] + bias;
    vp += __shfl_xor(vp, 16, 64);
    vp += __shfl_xor(vp, 32, 64);
    if (q == 0) atomicAdd(&sumv[b * 64 + w * 16 + n], vp);
  }
}

// ---------------- K2a: LDS-staged-K 2-tile top-8, 4-wave blocks -------------
// block=256 = 4 waves sharing ONE split (4 different 2-tile groups). The
// split's K (208 rows x 128B) is staged once into LDS, XOR-swizzled
// (slot ^= row&7) for bank-spread ds_read_b128 (G4). 2 tiles/wave doubles
// wave count vs the 4-tile version: 6400 waves, 4 resident/SIMD under
// launch_bounds(256,4) (VGPR ~82 << 128 budget, no spill; LDS 26.6KB -> 4
// blocks/CU). More TLP fills the sort's dependency/convoy stalls. Candidate
// packing/klim masking identical -> bit-exact top-8.
#define PAIRMERGE(T, accA, accB, jb) { \
    unsigned int _p0 = packB(accA[0], (jb) + 0); \
    unsigned int _p1 = packB(accA[1], (jb) + 1); \
    unsigned int _p2 = packB(accA[2], (jb) + 2); \
    unsigned int _p3 = packB(accA[3], (jb) + 3); \
    unsigned int _q0 = packB(accB[0], (jb) + 16); \
    unsigned int _q1 = packB(accB[1], (jb) + 17); \
    unsigned int _q2 = packB(accB[2], (jb) + 18); \
    unsigned int _q3 = packB(accB[3], (jb) + 19); \
    CSWAP(_p0, _p1); CSWAP(_p2, _p3); CSWAP(_p0, _p2); CSWAP(_p1, _p3); CSWAP(_p1, _p2); \
    CSWAP(_q0, _q1); CSWAP(_q2, _q3); CSWAP(_q0, _q2); CSWAP(_q1, _q3); CSWAP(_q1, _q2); \
    unsigned int _u8[8] = {_p0, _p1, _p2, _p3, _q3, _q2, _q1, _q0}; \
    BITONIC8(_u8); \
    T[0] = max(T[0], _u8[7]); \
    T[1] = max(T[1], _u8[6]); \
    T[2] = max(T[2], _u8[5]); \
    T[3] = max(T[3], _u8[4]); \
    T[4] = max(T[4], _u8[3]); \
    T[5] = max(T[5], _u8[2]); \
    T[6] = max(T[6], _u8[1]); \
    T[7] = max(T[7], _u8[0]); \
    BITONIC8(T); }

__global__ __launch_bounds__(256, 4) void k_attn_topk(
    const unsigned short* __restrict__ q16, const unsigned short* __restrict__ k16,
    unsigned int* __restrict__ top8out) {
  __shared__ __align__(16) unsigned short kS[13312];  // 26624 B = 208 rows x 128B (swizzled)
  int bid = blockIdx.x;
  int t = threadIdx.x;
  int w = t >> 6;
  int lane = t & 63;
  int tgq = bid % 25;
  int bs = bid / 25;              // 0..63
  int b = bs >> 4, split = bs & 15;
  int tg2 = tgq * 4 + w;          // 2-tile group 0..99 (>=98 idle)
  size_t bN = (size_t)b * Nv;
  int kbase = split * KPS;        // KPS=196

  // cooperative staging: 256 thr x 16B x 6.5 rounds; linear src, swizzled dst.
  // dst row = t>>3 (+32/round), slot = (t&7) ^ (row&7).
  {
    const char* src = (const char*)(k16 + bN * 64) + kbase * 128 + t * 16;
    char* dst = (char*)kS + (t >> 3) * 128 + (((t & 7) ^ ((t >> 3) & 7)) << 4);
#pragma unroll
    for (int r = 0; r < 6; ++r)
      *(uint4*)(dst + r * 4096) = *(const uint4*)(src + r * 4096);
    if (t < 128)
      *(uint4*)(dst + 6 * 4096) = *(const uint4*)(src + 6 * 4096);
  }
  __syncthreads();
  if (tg2 >= 98) return;

  int qbase = b * Nv + tg2 * 32;
  int qcol = lane & 15, quad = lane >> 4;
  int quad4 = quad * 4;
  int m = lane & 15;

  bf16x8 qf0a[2], qf1a[2];
#pragma unroll
  for (int tt = 0; tt < 2; ++tt) {
    qf0a[tt] = *(const bf16x8*)&q16[((size_t)(qbase + tt * 16 + qcol)) * 64 + quad * 8];
    qf1a[tt] = *(const bf16x8*)&q16[((size_t)(qbase + tt * 16 + qcol)) * 64 + 32 + quad * 8];
  }

  unsigned int t8[2][8];
#pragma unroll
  for (int tt = 0; tt < 2; ++tt)
#pragma unroll
    for (int u = 0; u < 8; ++u) t8[tt][u] = 0u;

  int jbA = kbase + quad4;
  // per-lane swizzled LDS pointers: row = m (+16/chunk), slots quad / quad+4
  int swz = m & 7;
  const char* pa = (const char*)kS + m * 128 + ((quad ^ swz) << 4);
  const char* pb = (const char*)kS + m * 128 + (((quad + 4) ^ swz) << 4);

#pragma unroll 1
  for (int it = 0; it < 6; ++it) {  // chunk pairs 0..5 = keys 0..191
    bf16x8 ca0 = *(const bf16x8*)(pa + it * 4096);
    bf16x8 ca1 = *(const bf16x8*)(pb + it * 4096);
    bf16x8 cb0 = *(const bf16x8*)(pa + it * 4096 + 2048);
    bf16x8 cb1 = *(const bf16x8*)(pb + it * 4096 + 2048);

#pragma unroll
    for (int tt = 0; tt < 2; ++tt) {
      f32x4 accA = {SBIAS, SBIAS, SBIAS, SBIAS};
      accA = __builtin_amdgcn_mfma_f32_16x16x32_bf16(ca0, qf0a[tt], accA, 0, 0, 0);
      accA = __builtin_amdgcn_mfma_f32_16x16x32_bf16(ca1, qf1a[tt], accA, 0, 0, 0);
      f32x4 accB = {SBIAS, SBIAS, SBIAS, SBIAS};
      accB = __builtin_amdgcn_mfma_f32_16x16x32_bf16(cb0, qf0a[tt], accB, 0, 0, 0);
      accB = __builtin_amdgcn_mfma_f32_16x16x32_bf16(cb1, qf1a[tt], accB, 0, 0, 0);
      PAIRMERGE(t8[tt], accA, accB, jbA);
    }
    jbA += 32;
  }

  {  // ragged chunk 12: rows 192..207 staged, keys 192..195 valid (klim mask)
    bf16x8 ka0 = *(const bf16x8*)(pa + 12 * 2048);
    bf16x8 ka1 = *(const bf16x8*)(pb + 12 * 2048);
    int klim = kbase + KPS;
#pragma unroll
    for (int tt = 0; tt < 2; ++tt) {
      f32x4 accA = {SBIAS, SBIAS, SBIAS, SBIAS};
      accA = __builtin_amdgcn_mfma_f32_16x16x32_bf16(ka0, qf0a[tt], accA, 0, 0, 0);
      accA = __builtin_amdgcn_mfma_f32_16x16x32_bf16(ka1, qf1a[tt], accA, 0, 0, 0);
      unsigned int p0 = (jbA + 0 < klim) ? packB(accA[0], jbA + 0) : 0u;
      unsigned int p1 = (jbA + 1 < klim) ? packB(accA[1], jbA + 1) : 0u;
      unsigned int p2 = (jbA + 2 < klim) ? packB(accA[2], jbA + 2) : 0u;
      unsigned int p3 = (jbA + 3 < klim) ? packB(accA[3], jbA + 3) : 0u;
      CSWAP(p0, p1); CSWAP(p2, p3); CSWAP(p0, p2); CSWAP(p1, p3); CSWAP(p1, p2);
      t8[tt][4] = max(t8[tt][4], p3);
      t8[tt][5] = max(t8[tt][5], p2);
      t8[tt][6] = max(t8[tt][6], p1);
      t8[tt][7] = max(t8[tt][7], p0);
      BITONIC8(t8[tt]);
    }
  }

  // merge across quads (same query col): butterfly xor 16, 32 — per tile
#pragma unroll
  for (int tt = 0; tt < 2; ++tt) {
#pragma unroll
    for (int step = 16; step <= 32; step <<= 1) {
      unsigned int o[8];
#pragma unroll
      for (int i = 0; i < 8; ++i) o[i] = (unsigned int)__shfl_xor((int)t8[tt][i], step, 64);
      unsigned int nw[8];
#pragma unroll
      for (int i = 0; i < 8; ++i) nw[i] = max(t8[tt][i], o[7 - i]);
#pragma unroll
      for (int i = 0; i < 8; ++i) t8[tt][i] = nw[i];
      BITONIC8(t8[tt]);
    }
    if (quad == 0) {
      size_t obase = ((size_t)(bN + tg2 * 32 + tt * 16 + qcol)) * 128 + split * 8;
      *(uint4*)&top8out[obase] = make_uint4(t8[tt][0], t8[tt][1], t8[tt][2], t8[tt][3]);
      *(uint4*)&top8out[obase + 4] = make_uint4(t8[tt][4], t8[tt][5], t8[tt][6], t8[tt][7]);
    }
  }
}

// ---- K2b: 16-list merge + PV + local-conv(fused) + proj + LN1 + res + LN2 --
// Phase A runs on wave 0 (4 lanes/token x 4 lists + 2-step butterfly),
// OVERLAPPED with im2col staging on waves 1-3. Phase B's 32 scattered vg
// gathers are issued before the conv MFMA loop so their latency hides.
__global__ __launch_bounds__(256) void k_attn_proj(
    const unsigned int* __restrict__ top8, const float* __restrict__ vg,
    const float* __restrict__ sumv, const float* __restrict__ x,
    const unsigned short* __restrict__ lwb, const float* __restrict__ lb,
    const unsigned short* __restrict__ wprojt, const float* __restrict__ bproj,
    const float* __restrict__ g1, const float* __restrict__ b1,
    const float* __restrict__ g2, const float* __restrict__ b2,
    float* __restrict__ x2, unsigned short* __restrict__ xn2b) {
  __shared__ float kwS[16][8];
  __shared__ int kidxS[16][8];
  __shared__ float invZS[16];
  __shared__ __align__(16) unsigned short imS[16 * LCP];
  __shared__ __align__(16) unsigned short gS[16 * XNP];
  __shared__ float yS[16 * 66];
  int bid = blockIdx.x;
  int b = bid / 196, rem = bid % 196;
  int th = rem / 7, tw = rem % 7;
  int h0 = th * 2, w0 = tw * 8;
  size_t bN = (size_t)b * Nv;
  int t = threadIdx.x;

  if (t < 64) {
    // Phase A (wave 0): parallel 16-list merge. lane group la=t&3 merges
    // lists 4*la..4*la+3 for token tk=t>>2, then butterfly xor 1,2.
    int tk = t >> 2, la = t & 3;
    int gtok = (h0 + (tk >> 3)) * Ww + w0 + (tk & 7);
    size_t base = (bN + gtok) * 128 + la * 32;
    unsigned int A[8];
#pragma unroll
    for (int i = 0; i < 8; ++i) A[i] = top8[base + i];
#pragma unroll
    for (int h = 1; h < 4; ++h) {
      unsigned int Bb[8];
#pragma unroll
      for (int i = 0; i < 8; ++i) Bb[i] = top8[base + h * 8 + i];
#pragma unroll
      for (int i = 0; i < 8; ++i) A[i] = max(A[i], Bb[7 - i]);
      BITONIC8(A);
    }
#pragma unroll
    for (int step = 1; step <= 2; step <<= 1) {
      unsigned int o[8];
#pragma unroll
      for (int i = 0; i < 8; ++i) o[i] = (unsigned int)__shfl_xor((int)A[i], step, 64);
#pragma unroll
      for (int i = 0; i < 8; ++i) A[i] = max(A[i], o[7 - i]);
      BITONIC8(A);
    }
    if (la == 0) {
      float Z = (float)(Nv - TOPKv);
#pragma unroll
      for (int u = 0; u < 8; ++u) {
        float sb = __uint_as_float(A[u] & 0xFFFFF000u);
        float s = (sb - SBIAS) * SCALE;
        float e = __expf(s);
        kwS[tk][u] = e - 1.0f;
        kidxS[tk][u] = (int)(A[u] & 0xFFFu);
        Z += e;
      }
      invZS[tk] = 1.0f / Z;
    }
  } else {
    // im2col staging from fp32 x (bf16 inline), waves 1-3: 1152/192 = 6 rounds
    for (int p = t - 64; p < 1152; p += 192) {
      int sub = p & 7, s = p >> 3;
      int tok = s / 9, tap = s % 9;
      int tr = tok >> 3, tc = tok & 7;
      int dh = tap / 3, dw = tap % 3;
      int gh = h0 + tr - 1 + dh, gw = w0 + tc - 1 + dw;
      uint4 uu = {0u, 0u, 0u, 0u};
      if (gh >= 0 && gh < Hh && gw >= 0 && gw < Ww) {
        const float* xp = &x[(bN + gh * Ww + gw) * 64 + sub * 8];
        float4 va = *(const float4*)xp;
        float4 vb = *(const float4*)(xp + 4);
        uu.x = pack2(va.x, va.y);
        uu.y = pack2(va.z, va.w);
        uu.z = pack2(vb.x, vb.y);
        uu.w = pack2(vb.z, vb.w);
      }
      *(uint4*)&imS[tok * LCP + tap * 64 + sub * 8] = uu;
    }
  }
  __syncthreads();

  int w = t >> 6, l = t & 63;
  int n = l & 15, q = l >> 4;

  // Phase B part 1: issue the 32 scattered vg gathers (latency hides under conv)
  int c = t & 63, rg = t >> 6;
  float vgv[4][8];
#pragma unroll
  for (int rr = 0; rr < 4; ++rr) {
    int tokL = rg * 4 + rr;
#pragma unroll
    for (int u = 0; u < 8; ++u)
      vgv[rr][u] = vg[(bN + kidxS[tokL][u]) * 64 + c];
  }

  // local conv MFMA (18 per wave), result in registers
  f32x4 lacc = {0.f, 0.f, 0.f, 0.f};
  {
    const unsigned short* lwrow = &lwb[(size_t)(w * 16 + n) * 576];
#pragma unroll 6
    for (int kk = 0; kk < 18; ++kk) {
      bf16x8 af = *(const bf16x8*)&imS[n * LCP + kk * 32 + q * 8];
      bf16x8 bfr = *(const bf16x8*)&lwrow[kk * 32 + q * 8];
      lacc = __builtin_amdgcn_mfma_f32_16x16x32_bf16(af, bfr, lacc, 0, 0, 0);
    }
  }
  float lbias = lb[w * 16 + n];

  // Phase B part 2: g = (sumv + sum_top8 (e^s-1) v)/Z -> gS (bf16)
  {
    float sv = sumv[b * 64 + c];
#pragma unroll
    for (int rr = 0; rr < 4; ++rr) {
      int tokL = rg * 4 + rr;
      float acc = sv;
#pragma unroll
      for (int u = 0; u < 8; ++u)
        acc += kwS[tokL][u] * vgv[rr][u];
      gS[tokL * XNP + c] = f2bf(acc * invZS[tokL]);
    }
  }
  __syncthreads();

  // Phase C: proj GEMM + add local conv, y -> yS
  {
    const bf16x8 a0 = *(const bf16x8*)&gS[n * XNP + q * 8];
    const bf16x8 a1 = *(const bf16x8*)&gS[n * XNP + 32 + q * 8];
    const unsigned short* wr = &wprojt[(size_t)(w * 16 + n) * 64];
    bf16x8 b0 = *(const bf16x8*)&wr[q * 8];
    bf16x8 b1_ = *(const bf16x8*)&wr[32 + q * 8];
    f32x4 acc = {0.f, 0.f, 0.f, 0.f};
    acc = __builtin_amdgcn_mfma_f32_16x16x32_bf16(a0, b0, acc, 0, 0, 0);
    acc = __builtin_amdgcn_mfma_f32_16x16x32_bf16(a1, b1_, acc, 0, 0, 0);
    float bias = bproj[w * 16 + n];
#pragma unroll
    for (int r = 0; r < 4; ++r)
      yS[(q * 4 + r) * 66 + w * 16 + n] = acc[r] + bias + lacc[r] + lbias;
  }
  __syncthreads();

  // Phase D: LN1 -> residual -> LN2 (16-lane group per token, 4 ch each)
  int tokL = t >> 4;
  int ch0 = (t & 15) * 4;
  size_t tok = bN + (size_t)(h0 + (tokL >> 3)) * Ww + w0 + (tokL & 7);
  float y[4];
#pragma unroll
  for (int i = 0; i < 4; ++i) y[i] = yS[tokL * 66 + ch0 + i];
  float s = y[0] + y[1] + y[2] + y[3];
  float s2 = y[0] * y[0] + y[1] * y[1] + y[2] * y[2] + y[3] * y[3];
#pragma unroll
  for (int off = 1; off <= 8; off <<= 1) {
    s += __shfl_xor(s, off, 64);
    s2 += __shfl_xor(s2, off, 64);
  }
  float m1 = s * (1.f / 64.f);
  float rs1 = rsqrtf(s2 * (1.f / 64.f) - m1 * m1 + EPS);
  float xv[4];
  *(float4*)xv = *(const float4*)&x[tok * 64 + ch0];
  float x2v[4];
  float t_s = 0.f, t_s2 = 0.f;
#pragma unroll
  for (int i = 0; i < 4; ++i) {
    float t1 = (y[i] - m1) * rs1 * g1[ch0 + i] + b1[ch0 + i];
    x2v[i] = xv[i] + t1;
    t_s += x2v[i];
    t_s2 += x2v[i] * x2v[i];
  }
#pragma unroll
  for (int off = 1; off <= 8; off <<= 1) {
    t_s += __shfl_xor(t_s, off, 64);
    t_s2 += __shfl_xor(t_s2, off, 64);
  }
  float m2 = t_s * (1.f / 64.f);
  float rs2 = rsqrtf(t_s2 * (1.f / 64.f) - m2 * m2 + EPS);
  *(float4*)&x2[tok * 64 + ch0] = *(float4*)x2v;
  unsigned int pk[2];
  {
    float a0_ = (x2v[0] - m2) * rs2 * g2[ch0] + b2[ch0];
    float a1_ = (x2v[1] - m2) * rs2 * g2[ch0 + 1] + b2[ch0 + 1];
    float a2_ = (x2v[2] - m2) * rs2 * g2[ch0 + 2] + b2[ch0 + 2];
    float a3_ = (x2v[3] - m2) * rs2 * g2[ch0 + 3] + b2[ch0 + 3];
    pk[0] = pack2(a0_, a1_);
    pk[1] = pack2(a2_, a3_);
  }
  *(uint2*)&xn2b[tok * 64 + ch0] = *(uint2*)pk;
}

// ---------------- K5: MSFN — depthwise in regs, 1x1 via MFMA ----------------
// xtS LDS staging (R3-proven): halo read once, reused by all 4 wave-groups.
__global__ __launch_bounds__(256) void k_msfn(
    const unsigned short* __restrict__ xn2b, const float* __restrict__ x2,
    const float* __restrict__ w3t, const float* __restrict__ b3,
    const float* __restrict__ w5t, const float* __restrict__ b5,
    const unsigned short* __restrict__ w1bf, const float* __restrict__ b1,
    float* __restrict__ out) {
  __shared__ __align__(16) unsigned short xtS[6 * 12 * 64];
  __shared__ __align__(16) unsigned short tsS[16 * TSP];

  int bid = blockIdx.x;
  int b = bid / 196;
  int rem = bid % 196;
  int th = rem / 7, tw = rem % 7;
  int h0 = th * 2, w0 = tw * 8;
  size_t bN = (size_t)b * Nv;
  int t = threadIdx.x;

  unsigned int* xtU = (unsigned int*)xtS;
  for (int p = t; p < 6 * 12 * 32; p += 256) {
    int cp = p & 31, rc = p >> 5;
    int r = rc / 12, cc = rc % 12;
    int gh = h0 - 2 + r, gw = w0 - 2 + cc;
    unsigned int v = 0;
    if (gh >= 0 && gh < Hh && gw >= 0 && gw < Ww)
      v = *(const unsigned int*)&xn2b[(bN + gh * Ww + gw) * 64 + cp * 2];
    xtU[rc * 32 + cp] = v;
  }
  __syncthreads();

  int cin = t & 63, tg = t >> 6;
  int tr = tg >> 1, tc0 = (tg & 1) * 4;
  float win[5][8];
#pragma unroll
  for (int r = 0; r < 5; ++r)
#pragma unroll
    for (int c = 0; c < 8; ++c)
      win[r][c] = bf2f(xtS[((tr + r) * 12 + tc0 + c) * 64 + cin]);

  unsigned int* tsU = (unsigned int*)tsS;
#pragma unroll 1
  for (int m2 = 0; m2 < 4; m2 += 2) {
    float a3[2][9], a5[2][25], bb3[2], bb5[2];
#pragma unroll
    for (int mm = 0; mm < 2; ++mm) {
      int m = m2 + mm;
#pragma unroll
      for (int tap = 0; tap < 9; ++tap) a3[mm][tap] = w3t[(tap * 4 + m) * 64 + cin];
#pragma unroll
      for (int tap = 0; tap < 25; ++tap) a5[mm][tap] = w5t[(tap * 4 + m) * 64 + cin];
      bb3[mm] = b3[cin * 4 + m];
      bb5[mm] = b5[cin * 4 + m];
    }
#pragma unroll
    for (int tk = 0; tk < 4; ++tk) {
      int tok = tg * 4 + tk;
      unsigned int p3 = 0, p5 = 0;
#pragma unroll
      for (int mm = 0; mm < 2; ++mm) {
        float acc3 = bb3[mm];
#pragma unroll
        for (int kh = 0; kh < 3; ++kh)
#pragma unroll
          for (int kw2 = 0; kw2 < 3; ++kw2)
            acc3 += win[1 + kh][tk + 1 + kw2] * a3[mm][kh * 3 + kw2];
        float acc5 = bb5[mm];
#pragma unroll
        for (int kh = 0; kh < 5; ++kh)
#pragma unroll
          for (int kw2 = 0; kw2 < 5; ++kw2)
            acc5 += win[kh][tk + kw2] * a5[mm][kh * 5 + kw2];
        p3 |= (unsigned int)f2bf(acc3) << (16 * mm);
        p5 |= (unsigned int)f2bf(acc5) << (16 * mm);
      }
      tsU[(tok * TSP + cin * 4 + m2) >> 1] = p3;
      tsU[(tok * TSP + 256 + cin * 4 + m2) >> 1] = p5;
    }
  }
  __syncthreads();

  int wv = tg, lane = t & 63;
  int n16 = lane & 15, quad = lane >> 4;
  const unsigned short* wrow = &w1bf[(size_t)(wv * 16 + n16) * 512];
  f32x4 acc = {0.f, 0.f, 0.f, 0.f};
#pragma unroll 4
  for (int kk = 0; kk < 16; ++kk) {
    bf16x8 af = *(const bf16x8*)&tsS[n16 * TSP + kk * 32 + quad * 8];
    bf16x8 bfr = *(const bf16x8*)&wrow[kk * 32 + quad * 8];
    acc = __builtin_amdgcn_mfma_f32_16x16x32_bf16(af, bfr, acc, 0, 0, 0);
  }
  float bias = b1[wv * 16 + n16];
#pragma unroll
  for (int r = 0; r < 4; ++r) {
    int tok = quad * 4 + r;
    int trr = tok >> 3, tcc = tok & 7;
    size_t idx = (bN + (size_t)(h0 + trr) * Ww + w0 + tcc) * 64 + wv * 16 + n16;
    out[idx] = x2[idx] + acc[r] + bias;
  }
}

extern "C" void kernel_launch(void* const* d_in, const int* in_sizes, int n_in,
                              void* d_out, int out_size, void* d_ws, size_t ws_size,
                              hipStream_t stream) {
  const float* x = (const float*)d_in[0];
  const float* n1g = (const float*)d_in[1];
  const float* n1b = (const float*)d_in[2];
  const float* wq = (const float*)d_in[3];
  const float* bq = (const float*)d_in[4];
  const float* wkv = (const float*)d_in[5];
  const float* bkv = (const float*)d_in[6];
  const float* wproj = (const float*)d_in[7];
  const float* bproj = (const float*)d_in[8];
  const float* lw = (const float*)d_in[9];
  const float* lb = (const float*)d_in[10];
  const float* n2g = (const float*)d_in[11];
  const float* n2b = (const float*)d_in[12];
  const float* w3 = (const float*)d_in[13];
  const float* b3 = (const float*)d_in[14];
  const float* w5 = (const float*)d_in[15];
  const float* b5 = (const float*)d_in[16];
  const float* w1 = (const float*)d_in[17];
  const float* b1 = (const float*)d_in[18];
  float* out = (float*)d_out;

  float* ws = (float*)d_ws;
  const size_t TOK = (size_t)Bv * Nv * Cv;  // 802816
  float* vb = ws;
  float* sumv = vb + TOK;            // 256
  float* x2 = sumv + 256;
  float* w3t = x2 + TOK;             // 2304
  float* w5t = w3t + 2304;           // 6400
  float* qkvb = w5t + 6400;          // 192
  unsigned short* q16 = (unsigned short*)(qkvb + 192);
  unsigned short* k16 = q16 + TOK;
  unsigned short* xn2b = k16 + TOK;
  unsigned short* w1bf = xn2b + TOK;       // 64*512
  unsigned short* lwb = w1bf + 64 * 512;   // 64*576
  unsigned short* wqkvt = lwb + 64 * 576;  // 192*64
  unsigned short* wprojt = wqkvt + 192 * 64;  // 64*64
  unsigned int* top8ws = (unsigned int*)(wprojt + 64 * 64 + 64);  // 12544*128 uints

  k_transpose<<<144, 256, 0, stream>>>(w1, lw, w3, w5, wq, wkv, bq, bkv, wproj,
                                       w1bf, lwb, w3t, w5t, wqkvt, qkvb, wprojt, sumv);
  k_ln_qkv<<<Bv * 196, 256, 0, stream>>>(x, n1g, n1b, wqkvt, qkvb, q16, k16, vb, sumv);
  k_attn_topk<<<Bv * 16 * 25, 256, 0, stream>>>(q16, k16, top8ws);
  k_attn_proj<<<Bv * 196, 256, 0, stream>>>(top8ws, vb, sumv, x, lwb, lb, wprojt, bproj,
                                            n1g, n1b, n2g, n2b, x2, xn2b);
  k_msfn<<<Bv * 196, 256, 0, stream>>>(xn2b, x2, w3t, b3, w5t, b5, w1bf, b1, out);
}